// Round 1
// baseline (674.161 us; speedup 1.0000x reference)
//
#include <hip/hip_runtime.h>
#include <stdint.h>

#define K_SEL 5000
#define NQ    262144   // 512*512
#define NB    2

// ---------------- workspace layout (uint32 words) ----------------
// [0..1]   prefix[b]
// [2..3]   rem[b]
// [4..5]   T[b]     (exact threshold value bits)
// [6..7]   need[b]  (# of ties to take, smallest-index first)
// [8..9]   selCount[b]
// [10..11] eqCount[b]
// [16..2063]        hist: 4 rounds x 2 batches x 256 bins
// [2064..12063]     selList: 2 x 5000
// [12064..20255]    eqList:  2 x 4096
#define WS_HIST 16
#define WS_SEL  2064
#define WS_EQ   12064
#define EQ_CAP  4096

__global__ void init_kernel(uint32_t* st) {
    for (int i = threadIdx.x; i < WS_HIST + 4 * 512; i += 256) st[i] = 0u;
    __syncthreads();
    if (threadIdx.x == 0) { st[2] = K_SEL; st[3] = K_SEL; }
}

__global__ void zero_ref_kernel(float* refout) {
    int t = blockIdx.x * 256 + threadIdx.x;   // 524288 total
    refout[t] = 0.0f;
}

__global__ void hist_kernel(const float* __restrict__ err, uint32_t* st, int round) {
    __shared__ uint32_t h[256];
    h[threadIdx.x] = 0u;
    __syncthreads();
    int t = blockIdx.x * 256 + threadIdx.x;       // 524288 total
    int b = t >> 18;
    uint32_t bits = __float_as_uint(err[t]);
    uint32_t pref = st[b];
    int shift = 24 - 8 * round;
    bool match = (round == 0) || ((bits >> (shift + 8)) == (pref >> (shift + 8)));
    if (match) atomicAdd(&h[(bits >> shift) & 255u], 1u);
    __syncthreads();
    uint32_t v = h[threadIdx.x];
    if (v) atomicAdd(&st[WS_HIST + round * 512 + b * 256 + threadIdx.x], v);
}

__global__ void scan_kernel(uint32_t* st, int round) {
    int b = blockIdx.x;
    int lane = threadIdx.x;                        // 64 lanes
    int shift = 24 - 8 * round;
    const uint32_t* hist = st + WS_HIST + round * 512 + b * 256;
    int binbase = 255 - 4 * lane;                  // descending chunks of 4
    uint32_t hv0 = hist[binbase], hv1 = hist[binbase - 1],
             hv2 = hist[binbase - 2], hv3 = hist[binbase - 3];
    uint32_t p = hv0 + hv1 + hv2 + hv3;
    uint32_t cum = p;
    for (int o = 1; o < 64; o <<= 1) {
        uint32_t n = __shfl_up(cum, o);
        if (lane >= o) cum += n;
    }
    uint32_t rem = st[2 + b];
    unsigned long long bal = __ballot(cum >= rem);
    int first = __ffsll(bal) - 1;
    if (lane == first) {
        uint32_t acc = cum - p;
        uint32_t hv[4] = {hv0, hv1, hv2, hv3};
        int chosen = binbase;
        for (int q = 0; q < 4; q++) {
            if (acc + hv[q] >= rem) { chosen = binbase - q; break; }
            acc += hv[q];
        }
        uint32_t pref = st[b] | ((uint32_t)chosen << shift);
        st[b] = pref;
        st[2 + b] = rem - acc;
        if (round == 3) { st[4 + b] = pref; st[6 + b] = rem - acc; }
    }
}

__global__ void compact_kernel(const float* __restrict__ err, uint32_t* st,
                               float* __restrict__ refout) {
    int t = blockIdx.x * 256 + threadIdx.x;
    int b = t >> 18;
    int i = t & (NQ - 1);
    uint32_t bits = __float_as_uint(err[t]);
    uint32_t T = st[4 + b];
    if (bits > T) {
        uint32_t slot = atomicAdd(&st[8 + b], 1u);
        st[WS_SEL + b * K_SEL + slot] = (uint32_t)i;
        refout[t] = 1.0f;                       // bits > T >= 0  =>  value > 0
    } else if (bits == T) {
        uint32_t e = atomicAdd(&st[10 + b], 1u);
        if (e < EQ_CAP) st[WS_EQ + b * EQ_CAP + e] = (uint32_t)i;
    }
}

__global__ void select_kernel(uint32_t* st, float* __restrict__ refout) {
    __shared__ uint32_t L[EQ_CAP];
    int b = blockIdx.x;
    uint32_t m = st[10 + b]; if (m > EQ_CAP) m = EQ_CAP;
    uint32_t need = st[6 + b];
    uint32_t T = st[4 + b];
    for (uint32_t j = threadIdx.x; j < m; j += blockDim.x) L[j] = st[WS_EQ + b * EQ_CAP + j];
    __syncthreads();
    for (uint32_t j = threadIdx.x; j < m; j += blockDim.x) {
        uint32_t idx = L[j];
        uint32_t rank = 0;
        for (uint32_t l = 0; l < m; l++) rank += (L[l] < idx) ? 1u : 0u;
        if (rank < need) {
            uint32_t slot = atomicAdd(&st[8 + b], 1u);
            st[WS_SEL + b * K_SEL + slot] = idx;
            refout[b * NQ + idx] = (T != 0u) ? 1.0f : 0.0f;
        }
    }
}

// 4x bilinear upsample of pha (2,1,512,512) -> (2,1,2048,2048), float4 stores
__global__ void upsample_kernel(const float* __restrict__ pha, float* __restrict__ out) {
    int t = blockIdx.x * 256 + threadIdx.x;       // 2*2048*512 total
    int xq = t & 511;
    int rest = t >> 9;
    int oy = rest & 2047;
    int b  = rest >> 11;
    const float* src = pha + (size_t)b * NQ;
    float sy = oy * 0.25f - 0.375f;
    sy = fminf(fmaxf(sy, 0.0f), 511.0f);
    int y0 = (int)sy; int y1i = min(y0 + 1, 511);
    float fy = sy - (float)y0;
    float rv[4];
#pragma unroll
    for (int j = 0; j < 4; j++) {
        int ox = xq * 4 + j;
        float sx = ox * 0.25f - 0.375f;
        sx = fminf(fmaxf(sx, 0.0f), 511.0f);
        int x0 = (int)sx; int x1i = min(x0 + 1, 511);
        float fx = sx - (float)x0;
        float v00 = src[y0 * 512 + x0],  v01 = src[y0 * 512 + x1i];
        float v10 = src[y1i * 512 + x0], v11 = src[y1i * 512 + x1i];
        rv[j] = v00 * (1.f - fy) * (1.f - fx) + v01 * (1.f - fy) * fx
              + v10 * fy * (1.f - fx)         + v11 * fy * fx;
    }
    float4 r4 = make_float4(rv[0], rv[1], rv[2], rv[3]);
    *reinterpret_cast<float4*>(out + (size_t)b * 4194304 + (size_t)oy * 2048 + xq * 4) = r4;
}

// one block (256 threads) per selected patch; full CNN in LDS
__global__ __launch_bounds__(256) void patch_kernel(
    const float* __restrict__ hid, const float* __restrict__ pha,
    const uint32_t* __restrict__ st,
    const float* __restrict__ w1, const float* __restrict__ g1, const float* __restrict__ bb1,
    const float* __restrict__ m1, const float* __restrict__ v1,
    const float* __restrict__ w2, const float* __restrict__ g2, const float* __restrict__ bb2,
    const float* __restrict__ m2, const float* __restrict__ v2,
    const float* __restrict__ w3, const float* __restrict__ g3, const float* __restrict__ bb3,
    const float* __restrict__ m3, const float* __restrict__ v3,
    const float* __restrict__ w4, const float* __restrict__ b4,
    float* __restrict__ out) {
    __shared__ float xin[33 * 64];   // [c][dy*8+dx]
    __shared__ float y1s[24 * 36];
    __shared__ float y2s[16 * 16];
    __shared__ float y3s[12 * 36];

    int bp = blockIdx.x;
    int b  = bp / K_SEL;
    int pi = bp - b * K_SEL;
    uint32_t idx = st[WS_SEL + b * K_SEL + pi];
    int hq = (int)(idx >> 9), wq = (int)(idx & 511u);
    int tid = threadIdx.x;

    // Stage A: gather 33x8x8 patch of the 2x-bilinear-upsampled concat(hid,pha)
    for (int q = tid; q < 33 * 64; q += 256) {
        int c = q >> 6, pos = q & 63, dy = pos >> 3, dx = pos & 7;
        int hy = hq * 2 + dy - 3, hx = wq * 2 + dx - 3;
        float val = 0.0f;
        if (hy >= 0 && hy < 1024 && hx >= 0 && hx < 1024) {
            float sy = hy * 0.5f - 0.25f; sy = fminf(fmaxf(sy, 0.f), 511.f);
            float sx = hx * 0.5f - 0.25f; sx = fminf(fmaxf(sx, 0.f), 511.f);
            int y0 = (int)sy, x0 = (int)sx;
            int y1i = min(y0 + 1, 511), x1i = min(x0 + 1, 511);
            float fy = sy - (float)y0, fx = sx - (float)x0;
            const float* src = (c < 32) ? hid + (size_t)(b * 32 + c) * NQ
                                        : pha + (size_t)b * NQ;
            float v00 = src[y0 * 512 + x0],  v01 = src[y0 * 512 + x1i];
            float v10 = src[y1i * 512 + x0], v11 = src[y1i * 512 + x1i];
            val = v00 * (1.f - fy) * (1.f - fx) + v01 * (1.f - fy) * fx
                + v10 * fy * (1.f - fx)         + v11 * fy * fx;
        }
        xin[q] = val;
    }
    __syncthreads();

    // conv1: 33->24, 8x8 -> 6x6, + BN + relu
    for (int o = tid; o < 24 * 36; o += 256) {
        int oc = o / 36, pos = o - oc * 36, oy = pos / 6, ox = pos - oy * 6;
        float acc = 0.f;
        const float* wrow = w1 + oc * 33 * 9;
        for (int ci = 0; ci < 33; ci++) {
            const float* xr = xin + ci * 64 + oy * 8 + ox;
            const float* wr = wrow + ci * 9;
#pragma unroll
            for (int ky = 0; ky < 3; ky++)
#pragma unroll
                for (int kx = 0; kx < 3; kx++)
                    acc += xr[ky * 8 + kx] * wr[ky * 3 + kx];
        }
        float sc = g1[oc] * rsqrtf(v1[oc] + 1e-5f);
        float sh = bb1[oc] - m1[oc] * sc;
        y1s[o] = fmaxf(acc * sc + sh, 0.f);
    }
    __syncthreads();

    // conv2: 24->16, 6x6 -> 4x4, + BN + relu (exactly 256 outputs)
    {
        int o = tid;
        int oc = o >> 4, pos = o & 15, oy = pos >> 2, ox = pos & 3;
        float acc = 0.f;
        const float* wrow = w2 + oc * 24 * 9;
        for (int ci = 0; ci < 24; ci++) {
            const float* xr = y1s + ci * 36 + oy * 6 + ox;
            const float* wr = wrow + ci * 9;
#pragma unroll
            for (int ky = 0; ky < 3; ky++)
#pragma unroll
                for (int kx = 0; kx < 3; kx++)
                    acc += xr[ky * 6 + kx] * wr[ky * 3 + kx];
        }
        float sc = g2[oc] * rsqrtf(v2[oc] + 1e-5f);
        float sh = bb2[oc] - m2[oc] * sc;
        y2s[o] = fmaxf(acc * sc + sh, 0.f);
    }
    __syncthreads();

    // conv3 on nearest-2x-upsampled y2 (16ch 8x8 via index>>1) -> 12ch 6x6, BN+relu
    for (int o = tid; o < 12 * 36; o += 256) {
        int oc = o / 36, pos = o - oc * 36, oy = pos / 6, ox = pos - oy * 6;
        float acc = 0.f;
        const float* wrow = w3 + oc * 16 * 9;
        for (int ci = 0; ci < 16; ci++) {
            const float* base = y2s + ci * 16;
            const float* wr = wrow + ci * 9;
#pragma unroll
            for (int ky = 0; ky < 3; ky++) {
                int yy = (oy + ky) >> 1;
#pragma unroll
                for (int kx = 0; kx < 3; kx++) {
                    int xx = (ox + kx) >> 1;
                    acc += base[yy * 4 + xx] * wr[ky * 3 + kx];
                }
            }
        }
        float sc = g3[oc] * rsqrtf(v3[oc] + 1e-5f);
        float sh = bb3[oc] - m3[oc] * sc;
        y3s[o] = fmaxf(acc * sc + sh, 0.f);
    }
    __syncthreads();

    // conv4: 12->1, 6x6 -> 4x4, + bias, scatter into pha_full
    if (tid < 16) {
        int r = tid >> 2, cc = tid & 3;
        float acc = 0.f;
        for (int ci = 0; ci < 12; ci++) {
            const float* xr = y3s + ci * 36 + r * 6 + cc;
            const float* wr = w4 + ci * 9;
#pragma unroll
            for (int ky = 0; ky < 3; ky++)
#pragma unroll
                for (int kx = 0; kx < 3; kx++)
                    acc += xr[ky * 6 + kx] * wr[ky * 3 + kx];
        }
        acc += b4[0];
        out[(size_t)b * 4194304 + (size_t)(hq * 4 + r) * 2048 + (wq * 4 + cc)] = acc;
    }
}

extern "C" void kernel_launch(void* const* d_in, const int* in_sizes, int n_in,
                              void* d_out, int out_size, void* d_ws, size_t ws_size,
                              hipStream_t stream) {
    const float* pha = (const float*)d_in[0];
    const float* err = (const float*)d_in[1];
    const float* hid = (const float*)d_in[2];
    const float* w1  = (const float*)d_in[3];
    const float* g1  = (const float*)d_in[4];
    const float* bb1 = (const float*)d_in[5];
    const float* m1  = (const float*)d_in[6];
    const float* v1  = (const float*)d_in[7];
    const float* w2  = (const float*)d_in[8];
    const float* g2  = (const float*)d_in[9];
    const float* bb2 = (const float*)d_in[10];
    const float* m2  = (const float*)d_in[11];
    const float* v2  = (const float*)d_in[12];
    const float* w3  = (const float*)d_in[13];
    const float* g3  = (const float*)d_in[14];
    const float* bb3 = (const float*)d_in[15];
    const float* v3  = (const float*)d_in[17];
    const float* m3  = (const float*)d_in[16];
    const float* w4  = (const float*)d_in[18];
    const float* b4  = (const float*)d_in[19];

    float* out    = (float*)d_out;
    float* refout = out + (size_t)NB * 4194304;   // after pha_full
    uint32_t* st  = (uint32_t*)d_ws;

    init_kernel<<<1, 256, 0, stream>>>(st);
    zero_ref_kernel<<<2048, 256, 0, stream>>>(refout);
    for (int r = 0; r < 4; r++) {
        hist_kernel<<<2048, 256, 0, stream>>>(err, st, r);
        scan_kernel<<<2, 64, 0, stream>>>(st, r);
    }
    compact_kernel<<<2048, 256, 0, stream>>>(err, st, refout);
    select_kernel<<<2, 256, 0, stream>>>(st, refout);
    upsample_kernel<<<8192, 256, 0, stream>>>(pha, out);
    patch_kernel<<<2 * K_SEL, 256, 0, stream>>>(hid, pha, st,
        w1, g1, bb1, m1, v1, w2, g2, bb2, m2, v2, w3, g3, bb3, m3, v3, w4, b4, out);
}

// Round 3
// 316.726 us; speedup vs baseline: 2.1285x; 2.1285x over previous
//
#include <hip/hip_runtime.h>
#include <stdint.h>

#define K_SEL 5000
#define NQ    262144   // 512*512
#define NB    2

// ---------------- ws layout (bytes) ----------------
// [0 .. 38912)    : 38 MFMA weight fragments (f16), frag*1024 + lane*16
//                   frags 0..17  conv1 (ky*6 + kx*2 + mt)
//                   frags 18..26 conv2 (ky*3 + kt)
//                   frags 27..35 conv3 (s = ky*3+kx)
//                   frags 36..37 conv1-pha (mt)
// BIAS_OFF        : 53 f32  (bias1[24], bias2[16], bias3[12], b4)
// W4_OFF          : w4rep [9][16] f32
// ST_OFF          : topk state (uint32 words, layout below)
#define BIAS_OFF 38912
#define W4_OFF   39424
#define ST_OFF   40960

// ---------------- topk state (uint32 word offsets within st) ----------------
// [0..1] prefix  [2..3] rem  [4..5] T  [6..7] need  [8..9] selCount  [10..11] eqCount
// [16..2063] hist 4x2x256 ; [2064..12063] selList 2x5000 ; [12064..20255] eqList 2x4096
#define WS_HIST 16
#define WS_SEL  2064
#define WS_EQ   12064
#define EQ_CAP  4096

typedef _Float16 f16x8 __attribute__((ext_vector_type(8)));
typedef _Float16 f16x4 __attribute__((ext_vector_type(4)));
typedef float    f32x4 __attribute__((ext_vector_type(4)));
#define MFMA16(a,b,c) __builtin_amdgcn_mfma_f32_16x16x32_f16(a,b,c,0,0,0)

// ================= weight prep: fold BN, pack MFMA fragments =================
__global__ void prep_kernel(const float* __restrict__ w1, const float* __restrict__ g1,
                            const float* __restrict__ b1, const float* __restrict__ m1,
                            const float* __restrict__ v1,
                            const float* __restrict__ w2, const float* __restrict__ g2,
                            const float* __restrict__ b2, const float* __restrict__ m2,
                            const float* __restrict__ v2,
                            const float* __restrict__ w3, const float* __restrict__ g3,
                            const float* __restrict__ b3, const float* __restrict__ m3,
                            const float* __restrict__ v3,
                            const float* __restrict__ w4, const float* __restrict__ b4,
                            char* __restrict__ ws) {
    _Float16* wf = (_Float16*)ws;
    float* bias = (float*)(ws + BIAS_OFF);
    float* w4r  = (float*)(ws + W4_OFF);
    int tid = threadIdx.x;
    for (int t = tid; t < 38 * 512; t += 256) {
        int frag = t >> 9, li = (t >> 3) & 63, j = t & 7;
        int lo = li & 15, hi = li >> 4;
        float val = 0.f;
        if (frag < 18) {                                  // conv1: k = kx*32 + ci
            int ky = frag / 6, r = frag % 6, kx = r >> 1, mt = r & 1;
            int oc = mt * 16 + lo, ci = hi * 8 + j;
            if (oc < 24) val = w1[((oc * 33 + ci) * 3 + ky) * 3 + kx] * g1[oc] * rsqrtf(v1[oc] + 1e-5f);
        } else if (frag < 27) {                           // conv2: k = kx*24 + ci  (k<72)
            int f = frag - 18, ky = f / 3, kt = f % 3;
            int oc = lo, k = kt * 32 + hi * 8 + j;
            if (k < 72) {
                int kx = k / 24, ci = k % 24;
                val = w2[((oc * 24 + ci) * 3 + ky) * 3 + kx] * g2[oc] * rsqrtf(v2[oc] + 1e-5f);
            }
        } else if (frag < 36) {                           // conv3: k = ci (<16)
            int s = frag - 27, ky = s / 3, kx = s % 3;
            int oc = lo, ci = hi * 8 + j;
            if (oc < 12 && ci < 16) val = w3[((oc * 16 + ci) * 3 + ky) * 3 + kx] * g3[oc] * rsqrtf(v3[oc] + 1e-5f);
        } else {                                          // conv1 pha channel: k = tap (<9)
            int mt = frag - 36, oc = mt * 16 + lo, tap = hi * 8 + j;
            if (oc < 24 && tap < 9)
                val = w1[((oc * 33 + 32) * 3 + tap / 3) * 3 + tap % 3] * g1[oc] * rsqrtf(v1[oc] + 1e-5f);
        }
        wf[t] = (_Float16)val;
    }
    if (tid < 53) {
        float v;
        if (tid < 24)      { float sc = g1[tid] * rsqrtf(v1[tid] + 1e-5f); v = b1[tid] - m1[tid] * sc; }
        else if (tid < 40) { int c = tid - 24; float sc = g2[c] * rsqrtf(v2[c] + 1e-5f); v = b2[c] - m2[c] * sc; }
        else if (tid < 52) { int c = tid - 40; float sc = g3[c] * rsqrtf(v3[c] + 1e-5f); v = b3[c] - m3[c] * sc; }
        else v = b4[0];
        bias[tid] = v;
    }
    if (tid < 144) { int t9 = tid / 16, ci = tid % 16; w4r[tid] = (ci < 12) ? w4[ci * 9 + t9] : 0.f; }
}

// ================= top-k machinery =================
__global__ void init_kernel(uint32_t* st) {
    for (int i = threadIdx.x; i < WS_HIST + 4 * 512; i += 256) st[i] = 0u;
    __syncthreads();
    if (threadIdx.x == 0) { st[2] = K_SEL; st[3] = K_SEL; }
}

__global__ void zero_ref_kernel(float* refout) {
    int t = blockIdx.x * 256 + threadIdx.x;
    refout[t] = 0.0f;
}

__global__ void hist_kernel(const float* __restrict__ err, uint32_t* st, int round) {
    __shared__ uint32_t h[256];
    h[threadIdx.x] = 0u;
    __syncthreads();
    int t = blockIdx.x * 256 + threadIdx.x;
    int b = t >> 18;
    uint32_t bits = __float_as_uint(err[t]);
    uint32_t pref = st[b];
    int shift = 24 - 8 * round;
    bool match = (round == 0) || ((bits >> (shift + 8)) == (pref >> (shift + 8)));
    if (match) atomicAdd(&h[(bits >> shift) & 255u], 1u);
    __syncthreads();
    uint32_t v = h[threadIdx.x];
    if (v) atomicAdd(&st[WS_HIST + round * 512 + b * 256 + threadIdx.x], v);
}

__global__ void scan_kernel(uint32_t* st, int round) {
    int b = blockIdx.x;
    int lane = threadIdx.x;
    int shift = 24 - 8 * round;
    const uint32_t* hist = st + WS_HIST + round * 512 + b * 256;
    int binbase = 255 - 4 * lane;
    uint32_t hv0 = hist[binbase], hv1 = hist[binbase - 1],
             hv2 = hist[binbase - 2], hv3 = hist[binbase - 3];
    uint32_t p = hv0 + hv1 + hv2 + hv3;
    uint32_t cum = p;
    for (int o = 1; o < 64; o <<= 1) {
        uint32_t n = __shfl_up(cum, o);
        if (lane >= o) cum += n;
    }
    uint32_t rem = st[2 + b];
    unsigned long long bal = __ballot(cum >= rem);
    int first = __ffsll(bal) - 1;
    if (lane == first) {
        uint32_t acc = cum - p;
        uint32_t hv[4] = {hv0, hv1, hv2, hv3};
        int chosen = binbase;
        for (int q = 0; q < 4; q++) {
            if (acc + hv[q] >= rem) { chosen = binbase - q; break; }
            acc += hv[q];
        }
        uint32_t pref = st[b] | ((uint32_t)chosen << shift);
        st[b] = pref;
        st[2 + b] = rem - acc;
        if (round == 3) { st[4 + b] = pref; st[6 + b] = rem - acc; }
    }
}

__global__ void compact_kernel(const float* __restrict__ err, uint32_t* st,
                               float* __restrict__ refout) {
    int t = blockIdx.x * 256 + threadIdx.x;
    int b = t >> 18;
    int i = t & (NQ - 1);
    uint32_t bits = __float_as_uint(err[t]);
    uint32_t T = st[4 + b];
    if (bits > T) {
        uint32_t slot = atomicAdd(&st[8 + b], 1u);
        st[WS_SEL + b * K_SEL + slot] = (uint32_t)i;
        refout[t] = 1.0f;
    } else if (bits == T) {
        uint32_t e = atomicAdd(&st[10 + b], 1u);
        if (e < EQ_CAP) st[WS_EQ + b * EQ_CAP + e] = (uint32_t)i;
    }
}

__global__ void select_kernel(uint32_t* st, float* __restrict__ refout) {
    __shared__ uint32_t L[EQ_CAP];
    int b = blockIdx.x;
    uint32_t m = st[10 + b]; if (m > EQ_CAP) m = EQ_CAP;
    uint32_t need = st[6 + b];
    uint32_t T = st[4 + b];
    for (uint32_t j = threadIdx.x; j < m; j += blockDim.x) L[j] = st[WS_EQ + b * EQ_CAP + j];
    __syncthreads();
    for (uint32_t j = threadIdx.x; j < m; j += blockDim.x) {
        uint32_t idx = L[j];
        uint32_t rank = 0;
        for (uint32_t q = 0; q < m; q++) rank += (L[q] < idx) ? 1u : 0u;
        if (rank < need) {
            uint32_t slot = atomicAdd(&st[8 + b], 1u);
            st[WS_SEL + b * K_SEL + slot] = idx;
            refout[b * NQ + idx] = (T != 0u) ? 1.0f : 0.0f;
        }
    }
}

// ================= 4x bilinear upsample of pha =================
__global__ void upsample_kernel(const float* __restrict__ pha, float* __restrict__ out) {
    int t = blockIdx.x * 256 + threadIdx.x;
    int xq = t & 511;
    int rest = t >> 9;
    int oy = rest & 2047;
    int b  = rest >> 11;
    const float* src = pha + (size_t)b * NQ;
    float sy = oy * 0.25f - 0.375f;
    sy = fminf(fmaxf(sy, 0.0f), 511.0f);
    int y0 = (int)sy; int y1i = min(y0 + 1, 511);
    float fy = sy - (float)y0;
    float rv[4];
#pragma unroll
    for (int j = 0; j < 4; j++) {
        int ox = xq * 4 + j;
        float sx = ox * 0.25f - 0.375f;
        sx = fminf(fmaxf(sx, 0.0f), 511.0f);
        int x0 = (int)sx; int x1i = min(x0 + 1, 511);
        float fx = sx - (float)x0;
        float v00 = src[y0 * 512 + x0],  v01 = src[y0 * 512 + x1i];
        float v10 = src[y1i * 512 + x0], v11 = src[y1i * 512 + x1i];
        rv[j] = v00 * (1.f - fy) * (1.f - fx) + v01 * (1.f - fy) * fx
              + v10 * fy * (1.f - fx)         + v11 * fy * fx;
    }
    float4 r4 = make_float4(rv[0], rv[1], rv[2], rv[3]);
    *reinterpret_cast<float4*>(out + (size_t)b * 4194304 + (size_t)oy * 2048 + xq * 4) = r4;
}

// ================= MFMA patch CNN: 2 waves / patch =================
__device__ __forceinline__ f16x8 ldfrag(const _Float16* wf, int frag, int l) {
    return *(const f16x8*)(wf + frag * 512 + l * 8);
}

__global__ __launch_bounds__(128) void patch_kernel(
    const float* __restrict__ hid, const float* __restrict__ pha,
    const char* __restrict__ ws, float* __restrict__ out) {
    // LDS: all row strides are odd multiples of 16B -> conflict-free b128
    __shared__ _Float16 xrep[64][104];   // [8x8 pos][kx*32 + ci], cols 96..103 = 0
    __shared__ _Float16 y1rep[36][104];  // [6x6 pos][kx*24 + oc], cols 72..103 = 0
    __shared__ _Float16 pool[64][56];    // phaRep [48][56] (conv1) then y2up [64][56] (conv3)
    __shared__ float pha8[64];
    __shared__ float biasL[56];
    float* y3s = (float*)&y1rep[0][0];   // [36][16] f32 (reused after conv2)

    const _Float16* wf = (const _Float16*)ws;
    const float* biasG = (const float*)(ws + BIAS_OFF);
    const float* w4r   = (const float*)(ws + W4_OFF);
    const uint32_t* st = (const uint32_t*)(ws + ST_OFF);

    int tid = threadIdx.x, l = tid & 63, wid = tid >> 6;
    int lo = l & 15, hi = l >> 4;
    int bp = blockIdx.x;
    int b = (bp >= K_SEL) ? 1 : 0;
    int pi = bp - b * K_SEL;
    uint32_t idx = st[WS_SEL + b * K_SEL + pi];
    int hq = (int)(idx >> 9), wq = (int)(idx & 511u);

    if (tid < 53) biasL[tid] = biasG[tid];

    // ---- gather: lane = 8x8 position, wave = 16-channel half ----
    int ry = l >> 3, rx = l & 7;
    int hy = hq * 2 + ry - 3, hx = wq * 2 + rx - 3;
    bool inb = ((unsigned)hy < 1024u) && ((unsigned)hx < 1024u);
    float sy = fminf(fmaxf(hy * 0.5f - 0.25f, 0.f), 511.f);
    float sx = fminf(fmaxf(hx * 0.5f - 0.25f, 0.f), 511.f);
    int y0 = (int)sy, x0 = (int)sx;
    int y1c = min(y0 + 1, 511), x1c = min(x0 + 1, 511);
    float fy = sy - (float)y0, fx = sx - (float)x0;
    int o00 = y0 * 512 + x0, o01 = y0 * 512 + x1c, o10 = y1c * 512 + x0, o11 = y1c * 512 + x1c;
    float w00 = (1.f - fy) * (1.f - fx), w01 = (1.f - fy) * fx;
    float w10 = fy * (1.f - fx), w11 = fy * fx;

    _Float16 hv[16];
    {
        const float* hb = hid + ((size_t)b * 32 + wid * 16) * NQ;
#pragma unroll
        for (int c = 0; c < 16; c++) {
            const float* p = hb + (size_t)c * NQ;
            float v = 0.f;
            if (inb) v = p[o00] * w00 + p[o01] * w01 + p[o10] * w10 + p[o11] * w11;
            hv[c] = (_Float16)v;
        }
    }
    f16x8 h0 = {hv[0], hv[1], hv[2], hv[3], hv[4], hv[5], hv[6], hv[7]};
    f16x8 h1 = {hv[8], hv[9], hv[10], hv[11], hv[12], hv[13], hv[14], hv[15]};
#pragma unroll
    for (int kx = 0; kx < 3; kx++) {
        int rx2 = rx - kx;
        if (rx2 >= 0) {
            _Float16* row = &xrep[ry * 8 + rx2][kx * 32 + wid * 16];
            *(f16x8*)row = h0;
            *((f16x8*)row + 1) = h1;
        }
    }
    f16x8 z8 = {(_Float16)0.f, (_Float16)0.f, (_Float16)0.f, (_Float16)0.f,
                (_Float16)0.f, (_Float16)0.f, (_Float16)0.f, (_Float16)0.f};
    if (wid == 0) {
        *(f16x8*)&xrep[l][96] = z8;        // k-pad
    } else {
        const float* p = pha + (size_t)b * NQ;
        float v = 0.f;
        if (inb) v = p[o00] * w00 + p[o01] * w01 + p[o10] * w10 + p[o11] * w11;
        pha8[l] = v;
    }
    __syncthreads();

    // ---- phaRep (wave0) + y1rep k-pad zero (wave1) ----
    if (wid == 0) {
        if (l < 48) {
            int py = (l * 43) >> 8, px = l - py * 6;
            *(f16x8*)&pool[l][8]  = z8;
            *(f16x8*)&pool[l][16] = z8;
            *(f16x8*)&pool[l][24] = z8;
#pragma unroll
            for (int t = 0; t < 9; t++) {
                int ky = t / 3, kx = t % 3;
                int ip = (py + ky) * 8 + px + kx;
                pool[l][t] = (_Float16)pha8[ip & 63];
            }
        }
    } else {
        for (int i = l; i < 144; i += 64) {
            int row = i >> 2, chunk = i & 3;
            *(f16x8*)&y1rep[row][72 + chunk * 8] = z8;
        }
    }
    __syncthreads();

    // ---- conv1: 33ch -> 24, 8x8 -> 6x6, MFMA ----
    // wave w owns output frags (mt0,nt=w),(mt1,nt=w),(mt=w,nt2)
    f32x4 zf = {0.f, 0.f, 0.f, 0.f};
    f32x4 aA0 = zf, aA1 = zf, aB = zf;
    int nA = wid * 16 + lo, nB = 32 + lo;
    int pyA = (nA * 43) >> 8, pxA = nA - pyA * 6;
    int pyB = (nB * 43) >> 8, pxB = nB - pyB * 6;
    {   // pha K-tile (taps 0..8 in k)
        f16x8 A0 = ldfrag(wf, 36, l), A1 = ldfrag(wf, 37, l);
        f16x8 BA = *(const f16x8*)&pool[nA][hi * 8];
        f16x8 BB = *(const f16x8*)&pool[nB][hi * 8];
        aA0 = MFMA16(A0, BA, aA0);
        aA1 = MFMA16(A1, BA, aA1);
        aB  = MFMA16(wid ? A1 : A0, BB, aB);
    }
#pragma unroll
    for (int ky = 0; ky < 3; ky++) {
#pragma unroll
        for (int kt = 0; kt < 3; kt++) {
            f16x8 A0 = ldfrag(wf, ky * 6 + kt * 2 + 0, l);
            f16x8 A1 = ldfrag(wf, ky * 6 + kt * 2 + 1, l);
            int rA = ((pyA + ky) * 8 + pxA) & 63;
            int rB = ((pyB + ky) * 8 + pxB) & 63;
            f16x8 BA = *(const f16x8*)&xrep[rA][kt * 32 + hi * 8];
            f16x8 BB = *(const f16x8*)&xrep[rB][kt * 32 + hi * 8];
            aA0 = MFMA16(A0, BA, aA0);
            aA1 = MFMA16(A1, BA, aA1);
            aB  = MFMA16(wid ? A1 : A0, BB, aB);
        }
    }
    // epilogue -> y1rep (bias+relu+f16, kx-replicated)
    {
        f32x4 accs[3] = {aA0, aA1, aB};
        int mts[3] = {0, 1, wid};
        int nts[3] = {wid, wid, 2};
#pragma unroll
        for (int f = 0; f < 3; f++) {
            int n = nts[f] * 16 + lo;
            int ocb = mts[f] * 16 + hi * 4;
            if (n < 36 && ocb < 24) {
                int py = (n * 43) >> 8, px = n - py * 6;
                f16x4 hh;
                hh[0] = (_Float16)fmaxf(accs[f][0] + biasL[ocb + 0], 0.f);
                hh[1] = (_Float16)fmaxf(accs[f][1] + biasL[ocb + 1], 0.f);
                hh[2] = (_Float16)fmaxf(accs[f][2] + biasL[ocb + 2], 0.f);
                hh[3] = (_Float16)fmaxf(accs[f][3] + biasL[ocb + 3], 0.f);
#pragma unroll
                for (int kx = 0; kx < 3; kx++) {
                    int px2 = px - kx;
                    if (px2 >= 0) *(f16x4*)&y1rep[py * 6 + px2][kx * 24 + ocb] = hh;
                }
            }
        }
    }
    __syncthreads();

    // ---- conv2 (wave0) : 24ch 6x6 -> 16ch 4x4 ; wave1 zeroes y2up pad ----
    if (wid == 0) {
        f32x4 a2 = zf;
        int qy = lo >> 2, qx = lo & 3;
#pragma unroll
        for (int ky = 0; ky < 3; ky++) {
#pragma unroll
            for (int kt = 0; kt < 3; kt++) {
                f16x8 A = ldfrag(wf, 18 + ky * 3 + kt, l);
                f16x8 B = *(const f16x8*)&y1rep[(qy + ky) * 6 + qx][kt * 32 + hi * 8];
                a2 = MFMA16(A, B, a2);
            }
        }
        int ocb = hi * 4;
        f16x4 hh;
        hh[0] = (_Float16)fmaxf(a2[0] + biasL[24 + ocb + 0], 0.f);
        hh[1] = (_Float16)fmaxf(a2[1] + biasL[24 + ocb + 1], 0.f);
        hh[2] = (_Float16)fmaxf(a2[2] + biasL[24 + ocb + 2], 0.f);
        hh[3] = (_Float16)fmaxf(a2[3] + biasL[24 + ocb + 3], 0.f);
#pragma unroll
        for (int dy = 0; dy < 2; dy++)
#pragma unroll
            for (int dx = 0; dx < 2; dx++) {
                int row = (2 * qy + dy) * 8 + 2 * qx + dx;
                *(f16x4*)&pool[row][ocb] = hh;     // y2up (nearest 2x)
            }
    } else {
        *(f16x8*)&pool[l][16] = z8;                // y2up k-pad 16..31
        *(f16x8*)&pool[l][24] = z8;
    }
    __syncthreads();

    // ---- conv3: 16ch 8x8 -> 12ch 6x6 ; wave0: nt0, wave1: nt1,nt2 ----
    f32x4 aC = zf, aD = zf;
    int nC = wid * 16 + lo, nD = 32 + lo;
    int pyC = (nC * 43) >> 8, pxC = nC - pyC * 6;
    int pyD = (nD * 43) >> 8, pxD = nD - pyD * 6;
#pragma unroll
    for (int s = 0; s < 9; s++) {
        int ky = s / 3, kx = s % 3;
        f16x8 A = ldfrag(wf, 27 + s, l);
        f16x8 BC = *(const f16x8*)&pool[((pyC + ky) * 8 + pxC + kx) & 63][hi * 8];
        aC = MFMA16(A, BC, aC);
        if (wid) {
            f16x8 BD = *(const f16x8*)&pool[((pyD + ky) * 8 + pxD + kx) & 63][hi * 8];
            aD = MFMA16(A, BD, aD);
        }
    }
    __syncthreads();   // y1rep reads done (conv2), safe to overwrite as y3s
    {
        int ocb = hi * 4;
        f32x4 accs[2] = {aC, aD};
        int nts[2] = {wid, 2};
        int cnt = wid ? 2 : 1;
        for (int f = 0; f < cnt; f++) {
            int n = nts[f] * 16 + lo;
            if (n < 36) {
                f32x4 v;
#pragma unroll
                for (int r = 0; r < 4; r++) {
                    float bb = (ocb + r < 12) ? biasL[40 + ocb + r] : 0.f;
                    float x = accs[f][r] + bb;
                    v[r] = (ocb + r < 12) ? fmaxf(x, 0.f) : 0.f;
                }
                *(f32x4*)&y3s[n * 16 + ocb] = v;
            }
        }
    }
    __syncthreads();

    // ---- conv4 (wave0): 12ch 6x6 -> 1ch 4x4, f32, + scatter store ----
    if (wid == 0) {
        int r4 = lo >> 2, c4 = lo & 3, cig = hi;
        float acc = 0.f;
#pragma unroll
        for (int t = 0; t < 9; t++) {
            int ky = t / 3, kx = t % 3;
            const f32x4 xv = *(const f32x4*)&y3s[((r4 + ky) * 6 + c4 + kx) * 16 + cig * 4];
            const f32x4 wv = *(const f32x4*)(w4r + t * 16 + cig * 4);
            acc += xv[0] * wv[0] + xv[1] * wv[1] + xv[2] * wv[2] + xv[3] * wv[3];
        }
        acc += __shfl_xor(acc, 32);
        acc += __shfl_xor(acc, 16);
        if (l < 16) {
            out[(size_t)b * 4194304 + (size_t)(hq * 4 + r4) * 2048 + (wq * 4 + c4)] = acc + biasL[52];
        }
    }
}

extern "C" void kernel_launch(void* const* d_in, const int* in_sizes, int n_in,
                              void* d_out, int out_size, void* d_ws, size_t ws_size,
                              hipStream_t stream) {
    const float* pha = (const float*)d_in[0];
    const float* err = (const float*)d_in[1];
    const float* hid = (const float*)d_in[2];
    const float* w1  = (const float*)d_in[3];
    const float* g1  = (const float*)d_in[4];
    const float* bb1 = (const float*)d_in[5];
    const float* m1  = (const float*)d_in[6];
    const float* v1  = (const float*)d_in[7];
    const float* w2  = (const float*)d_in[8];
    const float* g2  = (const float*)d_in[9];
    const float* bb2 = (const float*)d_in[10];
    const float* m2  = (const float*)d_in[11];
    const float* v2  = (const float*)d_in[12];
    const float* w3  = (const float*)d_in[13];
    const float* g3  = (const float*)d_in[14];
    const float* bb3 = (const float*)d_in[15];
    const float* m3  = (const float*)d_in[16];
    const float* v3  = (const float*)d_in[17];
    const float* w4  = (const float*)d_in[18];
    const float* b4  = (const float*)d_in[19];

    float* out    = (float*)d_out;
    float* refout = out + (size_t)NB * 4194304;
    char* ws      = (char*)d_ws;
    uint32_t* st  = (uint32_t*)(ws + ST_OFF);

    prep_kernel<<<1, 256, 0, stream>>>(w1, g1, bb1, m1, v1, w2, g2, bb2, m2, v2,
                                       w3, g3, bb3, m3, v3, w4, b4, ws);
    init_kernel<<<1, 256, 0, stream>>>(st);
    zero_ref_kernel<<<2048, 256, 0, stream>>>(refout);
    for (int r = 0; r < 4; r++) {
        hist_kernel<<<2048, 256, 0, stream>>>(err, st, r);
        scan_kernel<<<2, 64, 0, stream>>>(st, r);
    }
    compact_kernel<<<2048, 256, 0, stream>>>(err, st, refout);
    select_kernel<<<2, 256, 0, stream>>>(st, refout);
    upsample_kernel<<<8192, 256, 0, stream>>>(pha, out);
    patch_kernel<<<2 * K_SEL, 128, 0, stream>>>(hid, pha, ws, out);
}

// Round 6
// 202.178 us; speedup vs baseline: 3.3345x; 1.5666x over previous
//
#include <hip/hip_runtime.h>
#include <stdint.h>

#define K_SEL 5000
#define NQ    262144   // 512*512
#define NB    2

// ---------------- ws layout (bytes) ----------------
#define BIAS_OFF 38912
#define W4_OFF   39424
#define ST_OFF   40960

// ---------------- topk state (uint32 word offsets within st) ----------------
// [0..1] prefix  [2..3] rem  [4..5] T  [6..7] need  [8..9] selCount  [10..11] eqCount
// [16..2063] hist 4x2x256 ; [2064..12063] selList 2x5000 ; [12064..20255] eqList 2x4096
#define WS_HIST 16
#define WS_SEL  2064
#define WS_EQ   12064
#define EQ_CAP  4096

typedef _Float16 f16x8 __attribute__((ext_vector_type(8)));
typedef _Float16 f16x4 __attribute__((ext_vector_type(4)));
typedef float    f32x4 __attribute__((ext_vector_type(4)));
#define MFMA16(a,b,c) __builtin_amdgcn_mfma_f32_16x16x32_f16(a,b,c,0,0,0)

// ================= weight prep: fold BN, pack MFMA fragments, init topk state =================
__global__ void prep_kernel(const float* __restrict__ w1, const float* __restrict__ g1,
                            const float* __restrict__ b1, const float* __restrict__ m1,
                            const float* __restrict__ v1,
                            const float* __restrict__ w2, const float* __restrict__ g2,
                            const float* __restrict__ b2, const float* __restrict__ m2,
                            const float* __restrict__ v2,
                            const float* __restrict__ w3, const float* __restrict__ g3,
                            const float* __restrict__ b3, const float* __restrict__ m3,
                            const float* __restrict__ v3,
                            const float* __restrict__ w4, const float* __restrict__ b4,
                            char* __restrict__ ws) {
    _Float16* wf = (_Float16*)ws;
    float* bias = (float*)(ws + BIAS_OFF);
    float* w4r  = (float*)(ws + W4_OFF);
    uint32_t* st = (uint32_t*)(ws + ST_OFF);
    int tid = threadIdx.x;
    for (int t = tid; t < 38 * 512; t += 256) {
        int frag = t >> 9, li = (t >> 3) & 63, j = t & 7;
        int lo = li & 15, hi = li >> 4;
        float val = 0.f;
        if (frag < 18) {                                  // conv1: k = ci within fragment (ky,kx,mt)
            int ky = frag / 6, r = frag % 6, kx = r >> 1, mt = r & 1;
            int oc = mt * 16 + lo, ci = hi * 8 + j;
            if (oc < 24) val = w1[((oc * 33 + ci) * 3 + ky) * 3 + kx] * g1[oc] * rsqrtf(v1[oc] + 1e-5f);
        } else if (frag < 27) {                           // conv2: k = kx*24 + ci  (k<72)
            int f = frag - 18, ky = f / 3, kt = f % 3;
            int oc = lo, k = kt * 32 + hi * 8 + j;
            if (k < 72) {
                int kx = k / 24, ci = k % 24;
                val = w2[((oc * 24 + ci) * 3 + ky) * 3 + kx] * g2[oc] * rsqrtf(v2[oc] + 1e-5f);
            }
        } else if (frag < 36) {                           // conv3: k = ci (<16)
            int s = frag - 27, ky = s / 3, kx = s % 3;
            int oc = lo, ci = hi * 8 + j;
            if (oc < 12 && ci < 16) val = w3[((oc * 16 + ci) * 3 + ky) * 3 + kx] * g3[oc] * rsqrtf(v3[oc] + 1e-5f);
        } else {                                          // conv1 pha channel: k = tap (<9)
            int mt = frag - 36, oc = mt * 16 + lo, tap = hi * 8 + j;
            if (oc < 24 && tap < 9)
                val = w1[((oc * 33 + 32) * 3 + tap / 3) * 3 + tap % 3] * g1[oc] * rsqrtf(v1[oc] + 1e-5f);
        }
        wf[t] = (_Float16)val;
    }
    if (tid < 53) {
        float v;
        if (tid < 24)      { float sc = g1[tid] * rsqrtf(v1[tid] + 1e-5f); v = b1[tid] - m1[tid] * sc; }
        else if (tid < 40) { int c = tid - 24; float sc = g2[c] * rsqrtf(v2[c] + 1e-5f); v = b2[c] - m2[c] * sc; }
        else if (tid < 52) { int c = tid - 40; float sc = g3[c] * rsqrtf(v3[c] + 1e-5f); v = b3[c] - m3[c] * sc; }
        else v = b4[0];
        bias[tid] = v;
    }
    if (tid < 144) { int t9 = tid / 16, ci = tid % 16; w4r[tid] = (ci < 12) ? w4[ci * 9 + t9] : 0.f; }
    // topk state init
    for (int i = tid; i < WS_HIST + 4 * 512; i += 256) st[i] = 0u;
    __syncthreads();
    if (tid == 0) { st[2] = K_SEL; st[3] = K_SEL; }
}

// ================= top-k machinery =================
__global__ void hist_kernel(const float* __restrict__ err, uint32_t* st, int round) {
    __shared__ uint32_t h[256];
    h[threadIdx.x] = 0u;
    __syncthreads();
    int t = blockIdx.x * 256 + threadIdx.x;
    int b = t >> 18;
    uint32_t bits = __float_as_uint(err[t]);
    uint32_t pref = st[b];
    int shift = 24 - 8 * round;
    bool match = (round == 0) || ((bits >> (shift + 8)) == (pref >> (shift + 8)));
    if (match) atomicAdd(&h[(bits >> shift) & 255u], 1u);
    __syncthreads();
    uint32_t v = h[threadIdx.x];
    if (v) atomicAdd(&st[WS_HIST + round * 512 + b * 256 + threadIdx.x], v);
}

__global__ void scan_kernel(uint32_t* st, int round) {
    int b = blockIdx.x;
    int lane = threadIdx.x;
    int shift = 24 - 8 * round;
    const uint32_t* hist = st + WS_HIST + round * 512 + b * 256;
    int binbase = 255 - 4 * lane;
    uint32_t hv0 = hist[binbase], hv1 = hist[binbase - 1],
             hv2 = hist[binbase - 2], hv3 = hist[binbase - 3];
    uint32_t p = hv0 + hv1 + hv2 + hv3;
    uint32_t cum = p;
    for (int o = 1; o < 64; o <<= 1) {
        uint32_t n = __shfl_up(cum, o);
        if (lane >= o) cum += n;
    }
    uint32_t rem = st[2 + b];
    unsigned long long bal = __ballot(cum >= rem);
    int first = __ffsll(bal) - 1;
    if (lane == first) {
        uint32_t acc = cum - p;
        uint32_t hv[4] = {hv0, hv1, hv2, hv3};
        int chosen = binbase;
        for (int q = 0; q < 4; q++) {
            if (acc + hv[q] >= rem) { chosen = binbase - q; break; }
            acc += hv[q];
        }
        uint32_t pref = st[b] | ((uint32_t)chosen << shift);
        st[b] = pref;
        st[2 + b] = rem - acc;
        if (round == 3) { st[4 + b] = pref; st[6 + b] = rem - acc; }
    }
}

// compact + full refout write (replaces zero_ref). LDS-aggregated atomics.
__global__ void compact_kernel(const float* __restrict__ err, uint32_t* st,
                               float* __restrict__ refout) {
    __shared__ uint32_t selbuf[512];
    __shared__ uint32_t eqbuf[512];
    __shared__ uint32_t cnts[2];
    __shared__ uint32_t bases[2];
    int blk = blockIdx.x;                 // 1024 blocks; 512 per batch
    int b = blk >> 9;
    int base = (blk & 511) << 9;          // 512 elements per block
    if (threadIdx.x < 2) cnts[threadIdx.x] = 0u;
    __syncthreads();
    uint32_t T = st[4 + b];
#pragma unroll
    for (int it = 0; it < 2; it++) {
        int i = base + it * 256 + threadIdx.x;
        uint32_t bits = __float_as_uint(err[b * NQ + i]);
        float rv = 0.f;
        if (bits > T) {
            rv = 1.0f;
            uint32_t s = atomicAdd(&cnts[0], 1u);
            selbuf[s] = (uint32_t)i;
        } else if (bits == T) {
            uint32_t e = atomicAdd(&cnts[1], 1u);
            eqbuf[e] = (uint32_t)i;
        }
        refout[b * NQ + i] = rv;
    }
    __syncthreads();
    if (threadIdx.x == 0 && cnts[0]) bases[0] = atomicAdd(&st[8 + b], cnts[0]);
    if (threadIdx.x == 1 && cnts[1]) bases[1] = atomicAdd(&st[10 + b], cnts[1]);
    __syncthreads();
    for (uint32_t j = threadIdx.x; j < cnts[0]; j += 256) {
        uint32_t slot = bases[0] + j;
        if (slot < K_SEL) st[WS_SEL + b * K_SEL + slot] = selbuf[j];
    }
    for (uint32_t j = threadIdx.x; j < cnts[1]; j += 256) {
        uint32_t slot = bases[1] + j;
        if (slot < EQ_CAP) st[WS_EQ + b * EQ_CAP + slot] = eqbuf[j];
    }
}

__global__ void select_kernel(uint32_t* st, float* __restrict__ refout) {
    __shared__ uint32_t L[EQ_CAP];
    int b = blockIdx.x;
    uint32_t m = st[10 + b]; if (m > EQ_CAP) m = EQ_CAP;
    uint32_t need = st[6 + b];
    uint32_t T = st[4 + b];
    for (uint32_t j = threadIdx.x; j < m; j += blockDim.x) L[j] = st[WS_EQ + b * EQ_CAP + j];
    __syncthreads();
    for (uint32_t j = threadIdx.x; j < m; j += blockDim.x) {
        uint32_t idx = L[j];
        uint32_t rank = 0;
        for (uint32_t q = 0; q < m; q++) rank += (L[q] < idx) ? 1u : 0u;
        if (rank < need) {
            uint32_t slot = atomicAdd(&st[8 + b], 1u);
            if (slot < K_SEL) st[WS_SEL + b * K_SEL + slot] = idx;
            refout[b * NQ + idx] = (T != 0u) ? 1.0f : 0.0f;
        }
    }
}

// ================= 4x bilinear upsample of pha =================
__global__ void upsample_kernel(const float* __restrict__ pha, float* __restrict__ out) {
    int t = blockIdx.x * 256 + threadIdx.x;
    int xq = t & 511;
    int rest = t >> 9;
    int oy = rest & 2047;
    int b  = rest >> 11;
    const float* src = pha + (size_t)b * NQ;
    float sy = oy * 0.25f - 0.375f;
    sy = fminf(fmaxf(sy, 0.0f), 511.0f);
    int y0 = (int)sy; int y1i = min(y0 + 1, 511);
    float fy = sy - (float)y0;
    float rv[4];
#pragma unroll
    for (int j = 0; j < 4; j++) {
        int ox = xq * 4 + j;
        float sx = ox * 0.25f - 0.375f;
        sx = fminf(fmaxf(sx, 0.0f), 511.0f);
        int x0 = (int)sx; int x1i = min(x0 + 1, 511);
        float fx = sx - (float)x0;
        float v00 = src[y0 * 512 + x0],  v01 = src[y0 * 512 + x1i];
        float v10 = src[y1i * 512 + x0], v11 = src[y1i * 512 + x1i];
        rv[j] = v00 * (1.f - fy) * (1.f - fx) + v01 * (1.f - fy) * fx
              + v10 * fy * (1.f - fx)         + v11 * fy * fx;
    }
    float4 r4 = make_float4(rv[0], rv[1], rv[2], rv[3]);
    *reinterpret_cast<float4*>(out + (size_t)b * 4194304 + (size_t)oy * 2048 + xq * 4) = r4;
}

// ================= MFMA patch CNN: 2 waves / patch (R3 known-good version) =================
__device__ __forceinline__ f16x8 ldfrag(const _Float16* wf, int frag, int l) {
    return *(const f16x8*)(wf + frag * 512 + l * 8);
}

__global__ __launch_bounds__(128) void patch_kernel(
    const float* __restrict__ hid, const float* __restrict__ pha,
    const char* __restrict__ ws, float* __restrict__ out) {
    // LDS: all row strides are odd multiples of 16B -> conflict-free b128
    __shared__ _Float16 xrep[64][104];   // [8x8 pos][kx*32 + ci], cols 96..103 = 0
    __shared__ _Float16 y1rep[36][104];  // [6x6 pos][kx*24 + oc], cols 72..103 = 0
    __shared__ _Float16 pool[64][56];    // phaRep [48][56] (conv1) then y2up [64][56] (conv3)
    __shared__ float pha8[64];
    __shared__ float biasL[56];
    float* y3s = (float*)&y1rep[0][0];   // [36][16] f32 (reused after conv2)

    const _Float16* wf = (const _Float16*)ws;
    const float* biasG = (const float*)(ws + BIAS_OFF);
    const float* w4r   = (const float*)(ws + W4_OFF);
    const uint32_t* st = (const uint32_t*)(ws + ST_OFF);

    int tid = threadIdx.x, l = tid & 63, wid = tid >> 6;
    int lo = l & 15, hi = l >> 4;
    int bp = blockIdx.x;
    int b = (bp >= K_SEL) ? 1 : 0;
    int pi = bp - b * K_SEL;
    uint32_t idx = st[WS_SEL + b * K_SEL + pi] & 0x3FFFFu;   // clamp: fault-proof
    int hq = (int)(idx >> 9), wq = (int)(idx & 511u);

    if (tid < 53) biasL[tid] = biasG[tid];

    // ---- gather: lane = 8x8 position, wave = 16-channel half ----
    int ry = l >> 3, rx = l & 7;
    int hy = hq * 2 + ry - 3, hx = wq * 2 + rx - 3;
    bool inb = ((unsigned)hy < 1024u) && ((unsigned)hx < 1024u);
    float sy = fminf(fmaxf(hy * 0.5f - 0.25f, 0.f), 511.f);
    float sx = fminf(fmaxf(hx * 0.5f - 0.25f, 0.f), 511.f);
    int y0 = (int)sy, x0 = (int)sx;
    int y1c = min(y0 + 1, 511), x1c = min(x0 + 1, 511);
    float fy = sy - (float)y0, fx = sx - (float)x0;
    int o00 = y0 * 512 + x0, o01 = y0 * 512 + x1c, o10 = y1c * 512 + x0, o11 = y1c * 512 + x1c;
    float w00 = (1.f - fy) * (1.f - fx), w01 = (1.f - fy) * fx;
    float w10 = fy * (1.f - fx), w11 = fy * fx;

    _Float16 hv[16];
    {
        const float* hb = hid + ((size_t)b * 32 + wid * 16) * NQ;
#pragma unroll
        for (int c = 0; c < 16; c++) {
            const float* p = hb + (size_t)c * NQ;
            float v = 0.f;
            if (inb) v = p[o00] * w00 + p[o01] * w01 + p[o10] * w10 + p[o11] * w11;
            hv[c] = (_Float16)v;
        }
    }
    f16x8 h0 = {hv[0], hv[1], hv[2], hv[3], hv[4], hv[5], hv[6], hv[7]};
    f16x8 h1 = {hv[8], hv[9], hv[10], hv[11], hv[12], hv[13], hv[14], hv[15]};
#pragma unroll
    for (int kx = 0; kx < 3; kx++) {
        int rx2 = rx - kx;
        if (rx2 >= 0) {
            _Float16* row = &xrep[ry * 8 + rx2][kx * 32 + wid * 16];
            *(f16x8*)row = h0;
            *((f16x8*)row + 1) = h1;
        }
    }
    f16x8 z8 = {(_Float16)0.f, (_Float16)0.f, (_Float16)0.f, (_Float16)0.f,
                (_Float16)0.f, (_Float16)0.f, (_Float16)0.f, (_Float16)0.f};
    if (wid == 0) {
        *(f16x8*)&xrep[l][96] = z8;        // k-pad
    } else {
        const float* p = pha + (size_t)b * NQ;
        float v = 0.f;
        if (inb) v = p[o00] * w00 + p[o01] * w01 + p[o10] * w10 + p[o11] * w11;
        pha8[l] = v;
    }
    __syncthreads();

    // ---- phaRep (wave0) + y1rep k-pad zero (wave1) ----
    if (wid == 0) {
        if (l < 48) {
            int py = (l * 43) >> 8, px = l - py * 6;
            *(f16x8*)&pool[l][8]  = z8;
            *(f16x8*)&pool[l][16] = z8;
            *(f16x8*)&pool[l][24] = z8;
#pragma unroll
            for (int t = 0; t < 9; t++) {
                int ky = t / 3, kx = t % 3;
                int ip = (py + ky) * 8 + px + kx;
                pool[l][t] = (_Float16)pha8[ip & 63];
            }
        }
    } else {
        for (int i = l; i < 144; i += 64) {
            int row = i >> 2, chunk = i & 3;
            *(f16x8*)&y1rep[row][72 + chunk * 8] = z8;
        }
    }
    __syncthreads();

    // ---- conv1: 33ch -> 24, 8x8 -> 6x6, MFMA ----
    f32x4 zf = {0.f, 0.f, 0.f, 0.f};
    f32x4 aA0 = zf, aA1 = zf, aB = zf;
    int nA = wid * 16 + lo, nB = 32 + lo;
    int pyA = (nA * 43) >> 8, pxA = nA - pyA * 6;
    int pyB = (nB * 43) >> 8, pxB = nB - pyB * 6;
    {   // pha K-tile (taps in k)
        f16x8 A0 = ldfrag(wf, 36, l), A1 = ldfrag(wf, 37, l);
        f16x8 BA = *(const f16x8*)&pool[nA][hi * 8];
        f16x8 BB = *(const f16x8*)&pool[nB][hi * 8];
        aA0 = MFMA16(A0, BA, aA0);
        aA1 = MFMA16(A1, BA, aA1);
        aB  = MFMA16(wid ? A1 : A0, BB, aB);
    }
#pragma unroll
    for (int ky = 0; ky < 3; ky++) {
#pragma unroll
        for (int kt = 0; kt < 3; kt++) {
            f16x8 A0 = ldfrag(wf, ky * 6 + kt * 2 + 0, l);
            f16x8 A1 = ldfrag(wf, ky * 6 + kt * 2 + 1, l);
            int rA = ((pyA + ky) * 8 + pxA) & 63;
            int rB = ((pyB + ky) * 8 + pxB) & 63;
            f16x8 BA = *(const f16x8*)&xrep[rA][kt * 32 + hi * 8];
            f16x8 BB = *(const f16x8*)&xrep[rB][kt * 32 + hi * 8];
            aA0 = MFMA16(A0, BA, aA0);
            aA1 = MFMA16(A1, BA, aA1);
            aB  = MFMA16(wid ? A1 : A0, BB, aB);
        }
    }
    // epilogue -> y1rep (bias+relu+f16, kx-replicated)
    {
        f32x4 accs[3] = {aA0, aA1, aB};
        int mts[3] = {0, 1, wid};
        int nts[3] = {wid, wid, 2};
#pragma unroll
        for (int f = 0; f < 3; f++) {
            int n = nts[f] * 16 + lo;
            int ocb = mts[f] * 16 + hi * 4;
            if (n < 36 && ocb < 24) {
                int py = (n * 43) >> 8, px = n - py * 6;
                f16x4 hh;
                hh[0] = (_Float16)fmaxf(accs[f][0] + biasL[ocb + 0], 0.f);
                hh[1] = (_Float16)fmaxf(accs[f][1] + biasL[ocb + 1], 0.f);
                hh[2] = (_Float16)fmaxf(accs[f][2] + biasL[ocb + 2], 0.f);
                hh[3] = (_Float16)fmaxf(accs[f][3] + biasL[ocb + 3], 0.f);
#pragma unroll
                for (int kx = 0; kx < 3; kx++) {
                    int px2 = px - kx;
                    if (px2 >= 0) *(f16x4*)&y1rep[py * 6 + px2][kx * 24 + ocb] = hh;
                }
            }
        }
    }
    __syncthreads();

    // ---- conv2 (wave0) : 24ch 6x6 -> 16ch 4x4 ; wave1 zeroes y2up pad ----
    if (wid == 0) {
        f32x4 a2 = zf;
        int qy = lo >> 2, qx = lo & 3;
#pragma unroll
        for (int ky = 0; ky < 3; ky++) {
#pragma unroll
            for (int kt = 0; kt < 3; kt++) {
                f16x8 A = ldfrag(wf, 18 + ky * 3 + kt, l);
                f16x8 B = *(const f16x8*)&y1rep[(qy + ky) * 6 + qx][kt * 32 + hi * 8];
                a2 = MFMA16(A, B, a2);
            }
        }
        int ocb = hi * 4;
        f16x4 hh;
        hh[0] = (_Float16)fmaxf(a2[0] + biasL[24 + ocb + 0], 0.f);
        hh[1] = (_Float16)fmaxf(a2[1] + biasL[24 + ocb + 1], 0.f);
        hh[2] = (_Float16)fmaxf(a2[2] + biasL[24 + ocb + 2], 0.f);
        hh[3] = (_Float16)fmaxf(a2[3] + biasL[24 + ocb + 3], 0.f);
#pragma unroll
        for (int dy = 0; dy < 2; dy++)
#pragma unroll
            for (int dx = 0; dx < 2; dx++) {
                int row = (2 * qy + dy) * 8 + 2 * qx + dx;
                *(f16x4*)&pool[row][ocb] = hh;     // y2up (nearest 2x)
            }
    } else {
        *(f16x8*)&pool[l][16] = z8;                // y2up k-pad 16..31
        *(f16x8*)&pool[l][24] = z8;
    }
    __syncthreads();

    // ---- conv3: 16ch 8x8 -> 12ch 6x6 ; wave0: nt0, wave1: nt1,nt2 ----
    f32x4 aC = zf, aD = zf;
    int nC = wid * 16 + lo, nD = 32 + lo;
    int pyC = (nC * 43) >> 8, pxC = nC - pyC * 6;
    int pyD = (nD * 43) >> 8, pxD = nD - pyD * 6;
#pragma unroll
    for (int s = 0; s < 9; s++) {
        int ky = s / 3, kx = s % 3;
        f16x8 A = ldfrag(wf, 27 + s, l);
        f16x8 BC = *(const f16x8*)&pool[((pyC + ky) * 8 + pxC + kx) & 63][hi * 8];
        aC = MFMA16(A, BC, aC);
        if (wid) {
            f16x8 BD = *(const f16x8*)&pool[((pyD + ky) * 8 + pxD + kx) & 63][hi * 8];
            aD = MFMA16(A, BD, aD);
        }
    }
    __syncthreads();   // y1rep reads done (conv2), safe to overwrite as y3s
    {
        int ocb = hi * 4;
        f32x4 accs[2] = {aC, aD};
        int nts[2] = {wid, 2};
        int cnt = wid ? 2 : 1;
        for (int f = 0; f < cnt; f++) {
            int n = nts[f] * 16 + lo;
            if (n < 36) {
                f32x4 v;
#pragma unroll
                for (int r = 0; r < 4; r++) {
                    float bb = (ocb + r < 12) ? biasL[40 + ocb + r] : 0.f;
                    float x = accs[f][r] + bb;
                    v[r] = (ocb + r < 12) ? fmaxf(x, 0.f) : 0.f;
                }
                *(f32x4*)&y3s[n * 16 + ocb] = v;
            }
        }
    }
    __syncthreads();

    // ---- conv4 (wave0): 12ch 6x6 -> 1ch 4x4, f32, + scatter store ----
    if (wid == 0) {
        int r4 = lo >> 2, c4 = lo & 3, cig = hi;
        float acc = 0.f;
#pragma unroll
        for (int t = 0; t < 9; t++) {
            int ky = t / 3, kx = t % 3;
            const f32x4 xv = *(const f32x4*)&y3s[((r4 + ky) * 6 + c4 + kx) * 16 + cig * 4];
            const f32x4 wv = *(const f32x4*)(w4r + t * 16 + cig * 4);
            acc += xv[0] * wv[0] + xv[1] * wv[1] + xv[2] * wv[2] + xv[3] * wv[3];
        }
        acc += __shfl_xor(acc, 32);
        acc += __shfl_xor(acc, 16);
        if (l < 16) {
            out[(size_t)b * 4194304 + (size_t)(hq * 4 + r4) * 2048 + (wq * 4 + c4)] = acc + biasL[52];
        }
    }
}

extern "C" void kernel_launch(void* const* d_in, const int* in_sizes, int n_in,
                              void* d_out, int out_size, void* d_ws, size_t ws_size,
                              hipStream_t stream) {
    const float* pha = (const float*)d_in[0];
    const float* err = (const float*)d_in[1];
    const float* hid = (const float*)d_in[2];
    const float* w1  = (const float*)d_in[3];
    const float* g1  = (const float*)d_in[4];
    const float* bb1 = (const float*)d_in[5];
    const float* m1  = (const float*)d_in[6];
    const float* v1  = (const float*)d_in[7];
    const float* w2  = (const float*)d_in[8];
    const float* g2  = (const float*)d_in[9];
    const float* bb2 = (const float*)d_in[10];
    const float* m2  = (const float*)d_in[11];
    const float* v2  = (const float*)d_in[12];
    const float* w3  = (const float*)d_in[13];
    const float* g3  = (const float*)d_in[14];
    const float* bb3 = (const float*)d_in[15];
    const float* m3  = (const float*)d_in[16];
    const float* v3  = (const float*)d_in[17];
    const float* w4  = (const float*)d_in[18];
    const float* b4  = (const float*)d_in[19];

    float* out    = (float*)d_out;
    float* refout = out + (size_t)NB * 4194304;
    char* ws      = (char*)d_ws;
    uint32_t* st  = (uint32_t*)(ws + ST_OFF);

    prep_kernel<<<1, 256, 0, stream>>>(w1, g1, bb1, m1, v1, w2, g2, bb2, m2, v2,
                                       w3, g3, bb3, m3, v3, w4, b4, ws);
    for (int r = 0; r < 4; r++) {
        hist_kernel<<<2048, 256, 0, stream>>>(err, st, r);
        scan_kernel<<<2, 64, 0, stream>>>(st, r);
    }
    compact_kernel<<<1024, 256, 0, stream>>>(err, st, refout);
    select_kernel<<<2, 256, 0, stream>>>(st, refout);
    upsample_kernel<<<8192, 256, 0, stream>>>(pha, out);
    patch_kernel<<<2 * K_SEL, 128, 0, stream>>>(hid, pha, ws, out);
}

// Round 8
// 169.357 us; speedup vs baseline: 3.9807x; 1.1938x over previous
//
#include <hip/hip_runtime.h>
#include <stdint.h>

#define K_SEL 5000
#define NQ    262144   // 512*512
#define NB    2

// ---------------- ws layout (bytes) ----------------
#define BIAS_OFF 38912
#define W4_OFF   39424
#define ST_OFF   40960

// ---------------- topk state (uint32 word offsets within st) ----------------
// [0..1] prefix  [2..3] rem  [4..5] T  [6..7] need  [8..9] selCount  [10..11] eqCount
// [16..2063] hist 4x2x256 ; [2064..12063] selList 2x5000 ; [12064..20255] eqList 2x4096
#define WS_HIST 16
#define WS_SEL  2064
#define WS_EQ   12064
#define EQ_CAP  4096

typedef _Float16 f16x8 __attribute__((ext_vector_type(8)));
typedef _Float16 f16x4 __attribute__((ext_vector_type(4)));
typedef float    f32x4 __attribute__((ext_vector_type(4)));
#define MFMA16(a,b,c) __builtin_amdgcn_mfma_f32_16x16x32_f16(a,b,c,0,0,0)

// ================= weight prep: fold BN, pack MFMA fragments, init topk state =================
__global__ void prep_kernel(const float* __restrict__ w1, const float* __restrict__ g1,
                            const float* __restrict__ b1, const float* __restrict__ m1,
                            const float* __restrict__ v1,
                            const float* __restrict__ w2, const float* __restrict__ g2,
                            const float* __restrict__ b2, const float* __restrict__ m2,
                            const float* __restrict__ v2,
                            const float* __restrict__ w3, const float* __restrict__ g3,
                            const float* __restrict__ b3, const float* __restrict__ m3,
                            const float* __restrict__ v3,
                            const float* __restrict__ w4, const float* __restrict__ b4,
                            char* __restrict__ ws) {
    _Float16* wf = (_Float16*)ws;
    float* bias = (float*)(ws + BIAS_OFF);
    float* w4r  = (float*)(ws + W4_OFF);
    uint32_t* st = (uint32_t*)(ws + ST_OFF);
    int tid = threadIdx.x;
    for (int t = tid; t < 38 * 512; t += 256) {
        int frag = t >> 9, li = (t >> 3) & 63, j = t & 7;
        int lo = li & 15, hi = li >> 4;
        float val = 0.f;
        if (frag < 18) {                                  // conv1: k = ci within fragment (ky,kx,mt)
            int ky = frag / 6, r = frag % 6, kx = r >> 1, mt = r & 1;
            int oc = mt * 16 + lo, ci = hi * 8 + j;
            if (oc < 24) val = w1[((oc * 33 + ci) * 3 + ky) * 3 + kx] * g1[oc] * rsqrtf(v1[oc] + 1e-5f);
        } else if (frag < 27) {                           // conv2: k = kx*24 + ci  (k<72)
            int f = frag - 18, ky = f / 3, kt = f % 3;
            int oc = lo, k = kt * 32 + hi * 8 + j;
            if (k < 72) {
                int kx = k / 24, ci = k % 24;
                val = w2[((oc * 24 + ci) * 3 + ky) * 3 + kx] * g2[oc] * rsqrtf(v2[oc] + 1e-5f);
            }
        } else if (frag < 36) {                           // conv3: k = ci (<16)
            int s = frag - 27, ky = s / 3, kx = s % 3;
            int oc = lo, ci = hi * 8 + j;
            if (oc < 12 && ci < 16) val = w3[((oc * 16 + ci) * 3 + ky) * 3 + kx] * g3[oc] * rsqrtf(v3[oc] + 1e-5f);
        } else {                                          // conv1 pha channel: k = tap (<9)
            int mt = frag - 36, oc = mt * 16 + lo, tap = hi * 8 + j;
            if (oc < 24 && tap < 9)
                val = w1[((oc * 33 + 32) * 3 + tap / 3) * 3 + tap % 3] * g1[oc] * rsqrtf(v1[oc] + 1e-5f);
        }
        wf[t] = (_Float16)val;
    }
    if (tid < 53) {
        float v;
        if (tid < 24)      { float sc = g1[tid] * rsqrtf(v1[tid] + 1e-5f); v = b1[tid] - m1[tid] * sc; }
        else if (tid < 40) { int c = tid - 24; float sc = g2[c] * rsqrtf(v2[c] + 1e-5f); v = b2[c] - m2[c] * sc; }
        else if (tid < 52) { int c = tid - 40; float sc = g3[c] * rsqrtf(v3[c] + 1e-5f); v = b3[c] - m3[c] * sc; }
        else v = b4[0];
        bias[tid] = v;
    }
    if (tid < 144) { int t9 = tid / 16, ci = tid % 16; w4r[tid] = (ci < 12) ? w4[ci * 9 + t9] : 0.f; }
    // topk state init
    for (int i = tid; i < WS_HIST + 4 * 512; i += 256) st[i] = 0u;
    __syncthreads();
    if (tid == 0) { st[2] = K_SEL; st[3] = K_SEL; }
}

// ================= top-k machinery =================
__global__ void hist_kernel(const float* __restrict__ err, uint32_t* st, int round) {
    __shared__ uint32_t h[256];
    h[threadIdx.x] = 0u;
    __syncthreads();
    int t = blockIdx.x * 256 + threadIdx.x;
    int b = t >> 18;
    uint32_t bits = __float_as_uint(err[t]);
    uint32_t pref = st[b];
    int shift = 24 - 8 * round;
    bool match = (round == 0) || ((bits >> (shift + 8)) == (pref >> (shift + 8)));
    if (match) atomicAdd(&h[(bits >> shift) & 255u], 1u);
    __syncthreads();
    uint32_t v = h[threadIdx.x];
    if (v) atomicAdd(&st[WS_HIST + round * 512 + b * 256 + threadIdx.x], v);
}

__global__ void scan_kernel(uint32_t* st, int round) {
    int b = blockIdx.x;
    int lane = threadIdx.x;
    int shift = 24 - 8 * round;
    const uint32_t* hist = st + WS_HIST + round * 512 + b * 256;
    int binbase = 255 - 4 * lane;
    uint32_t hv0 = hist[binbase], hv1 = hist[binbase - 1],
             hv2 = hist[binbase - 2], hv3 = hist[binbase - 3];
    uint32_t p = hv0 + hv1 + hv2 + hv3;
    uint32_t cum = p;
    for (int o = 1; o < 64; o <<= 1) {
        uint32_t n = __shfl_up(cum, o);
        if (lane >= o) cum += n;
    }
    uint32_t rem = st[2 + b];
    unsigned long long bal = __ballot(cum >= rem);
    int first = __ffsll(bal) - 1;
    if (lane == first) {
        uint32_t acc = cum - p;
        uint32_t hv[4] = {hv0, hv1, hv2, hv3};
        int chosen = binbase;
        for (int q = 0; q < 4; q++) {
            if (acc + hv[q] >= rem) { chosen = binbase - q; break; }
            acc += hv[q];
        }
        uint32_t pref = st[b] | ((uint32_t)chosen << shift);
        st[b] = pref;
        st[2 + b] = rem - acc;
        if (round == 3) { st[4 + b] = pref; st[6 + b] = rem - acc; }
    }
}

// compact + full refout write (replaces zero_ref). LDS-aggregated atomics.
__global__ void compact_kernel(const float* __restrict__ err, uint32_t* st,
                               float* __restrict__ refout) {
    __shared__ uint32_t selbuf[512];
    __shared__ uint32_t eqbuf[512];
    __shared__ uint32_t cnts[2];
    __shared__ uint32_t bases[2];
    int blk = blockIdx.x;                 // 1024 blocks; 512 per batch
    int b = blk >> 9;
    int base = (blk & 511) << 9;          // 512 elements per block
    if (threadIdx.x < 2) cnts[threadIdx.x] = 0u;
    __syncthreads();
    uint32_t T = st[4 + b];
#pragma unroll
    for (int it = 0; it < 2; it++) {
        int i = base + it * 256 + threadIdx.x;
        uint32_t bits = __float_as_uint(err[b * NQ + i]);
        float rv = 0.f;
        if (bits > T) {
            rv = 1.0f;
            uint32_t s = atomicAdd(&cnts[0], 1u);
            selbuf[s] = (uint32_t)i;
        } else if (bits == T) {
            uint32_t e = atomicAdd(&cnts[1], 1u);
            eqbuf[e] = (uint32_t)i;
        }
        refout[b * NQ + i] = rv;
    }
    __syncthreads();
    if (threadIdx.x == 0 && cnts[0]) bases[0] = atomicAdd(&st[8 + b], cnts[0]);
    if (threadIdx.x == 1 && cnts[1]) bases[1] = atomicAdd(&st[10 + b], cnts[1]);
    __syncthreads();
    for (uint32_t j = threadIdx.x; j < cnts[0]; j += 256) {
        uint32_t slot = bases[0] + j;
        if (slot < K_SEL) st[WS_SEL + b * K_SEL + slot] = selbuf[j];
    }
    for (uint32_t j = threadIdx.x; j < cnts[1]; j += 256) {
        uint32_t slot = bases[1] + j;
        if (slot < EQ_CAP) st[WS_EQ + b * EQ_CAP + slot] = eqbuf[j];
    }
}

__global__ void select_kernel(uint32_t* st, float* __restrict__ refout) {
    __shared__ uint32_t L[EQ_CAP];
    int b = blockIdx.x;
    uint32_t m = st[10 + b]; if (m > EQ_CAP) m = EQ_CAP;
    uint32_t need = st[6 + b];
    uint32_t T = st[4 + b];
    for (uint32_t j = threadIdx.x; j < m; j += blockDim.x) L[j] = st[WS_EQ + b * EQ_CAP + j];
    __syncthreads();
    for (uint32_t j = threadIdx.x; j < m; j += blockDim.x) {
        uint32_t idx = L[j];
        uint32_t rank = 0;
        for (uint32_t q = 0; q < m; q++) rank += (L[q] < idx) ? 1u : 0u;
        if (rank < need) {
            uint32_t slot = atomicAdd(&st[8 + b], 1u);
            if (slot < K_SEL) st[WS_SEL + b * K_SEL + slot] = idx;
            refout[b * NQ + idx] = (T != 0u) ? 1.0f : 0.0f;
        }
    }
}

// ================= 4x bilinear upsample of pha =================
__global__ void upsample_kernel(const float* __restrict__ pha, float* __restrict__ out) {
    int t = blockIdx.x * 256 + threadIdx.x;
    int xq = t & 511;
    int rest = t >> 9;
    int oy = rest & 2047;
    int b  = rest >> 11;
    const float* src = pha + (size_t)b * NQ;
    float sy = oy * 0.25f - 0.375f;
    sy = fminf(fmaxf(sy, 0.0f), 511.0f);
    int y0 = (int)sy; int y1i = min(y0 + 1, 511);
    float fy = sy - (float)y0;
    float rv[4];
#pragma unroll
    for (int j = 0; j < 4; j++) {
        int ox = xq * 4 + j;
        float sx = ox * 0.25f - 0.375f;
        sx = fminf(fmaxf(sx, 0.0f), 511.0f);
        int x0 = (int)sx; int x1i = min(x0 + 1, 511);
        float fx = sx - (float)x0;
        float v00 = src[y0 * 512 + x0],  v01 = src[y0 * 512 + x1i];
        float v10 = src[y1i * 512 + x0], v11 = src[y1i * 512 + x1i];
        rv[j] = v00 * (1.f - fy) * (1.f - fx) + v01 * (1.f - fy) * fx
              + v10 * fy * (1.f - fx)         + v11 * fy * fx;
    }
    float4 r4 = make_float4(rv[0], rv[1], rv[2], rv[3]);
    *reinterpret_cast<float4*>(out + (size_t)b * 4194304 + (size_t)oy * 2048 + xq * 4) = r4;
}

// ================= MFMA patch CNN: 2 waves / patch =================
// vs R6: ONLY the conv1 input tile changed: xrep[64][104] -> xs[64][40]
// (non-replicated; conv1 B-read row includes the kt tap). No swizzle.
__device__ __forceinline__ f16x8 ldfrag(const _Float16* wf, int frag, int l) {
    return *(const f16x8*)(wf + frag * 512 + l * 8);
}

__global__ __launch_bounds__(128) void patch_kernel(
    const float* __restrict__ hid, const float* __restrict__ pha,
    const char* __restrict__ ws, float* __restrict__ out) {
    __shared__ _Float16 xs[64][40];      // [8x8 pos][ci], ci 0..31 valid; cols 32..39 unused pad
    __shared__ _Float16 y1rep[36][104];  // [6x6 pos][kx*24 + oc], cols 72..103 = 0
    __shared__ _Float16 pool[64][56];    // phaRep [48][56] (conv1) then y2up [64][56] (conv3)
    __shared__ float pha8[64];
    __shared__ float biasL[56];
    float* y3s = (float*)&y1rep[0][0];   // [36][16] f32 (reused after conv2)

    const _Float16* wf = (const _Float16*)ws;
    const float* biasG = (const float*)(ws + BIAS_OFF);
    const float* w4r   = (const float*)(ws + W4_OFF);
    const uint32_t* st = (const uint32_t*)(ws + ST_OFF);

    int tid = threadIdx.x, l = tid & 63, wid = tid >> 6;
    int lo = l & 15, hi = l >> 4;
    int bp = blockIdx.x;                 // no swizzle this round (bisect)
    int b = (bp >= K_SEL) ? 1 : 0;
    int pi = bp - b * K_SEL;
    uint32_t idx = st[WS_SEL + b * K_SEL + pi] & 0x3FFFFu;   // clamp: fault-proof
    int hq = (int)(idx >> 9), wq = (int)(idx & 511u);

    if (tid < 53) biasL[tid] = biasG[tid];

    // ---- gather: lane = 8x8 position, wave = 16-channel half ----
    int ry = l >> 3, rx = l & 7;
    int hy = hq * 2 + ry - 3, hx = wq * 2 + rx - 3;
    bool inb = ((unsigned)hy < 1024u) && ((unsigned)hx < 1024u);
    float sy = fminf(fmaxf(hy * 0.5f - 0.25f, 0.f), 511.f);
    float sx = fminf(fmaxf(hx * 0.5f - 0.25f, 0.f), 511.f);
    int y0 = (int)sy, x0 = (int)sx;
    int y1c = min(y0 + 1, 511), x1c = min(x0 + 1, 511);
    float fy = sy - (float)y0, fx = sx - (float)x0;
    int o00 = y0 * 512 + x0, o01 = y0 * 512 + x1c, o10 = y1c * 512 + x0, o11 = y1c * 512 + x1c;
    float w00 = (1.f - fy) * (1.f - fx), w01 = (1.f - fy) * fx;
    float w10 = fy * (1.f - fx), w11 = fy * fx;

    _Float16 hv[16];
    {
        const float* hb = hid + ((size_t)b * 32 + wid * 16) * NQ;
#pragma unroll
        for (int c = 0; c < 16; c++) {
            const float* p = hb + (size_t)c * NQ;
            float v = 0.f;
            if (inb) v = p[o00] * w00 + p[o01] * w01 + p[o10] * w10 + p[o11] * w11;
            hv[c] = (_Float16)v;
        }
    }
    f16x8 h0 = {hv[0], hv[1], hv[2], hv[3], hv[4], hv[5], hv[6], hv[7]};
    f16x8 h1 = {hv[8], hv[9], hv[10], hv[11], hv[12], hv[13], hv[14], hv[15]};
    {
        _Float16* xrow = &xs[l][wid * 16];
        *(f16x8*)xrow = h0;
        *((f16x8*)xrow + 1) = h1;
    }
    f16x8 z8 = {(_Float16)0.f, (_Float16)0.f, (_Float16)0.f, (_Float16)0.f,
                (_Float16)0.f, (_Float16)0.f, (_Float16)0.f, (_Float16)0.f};
    if (wid == 1) {
        const float* p = pha + (size_t)b * NQ;
        float v = 0.f;
        if (inb) v = p[o00] * w00 + p[o01] * w01 + p[o10] * w10 + p[o11] * w11;
        pha8[l] = v;
    }
    __syncthreads();

    // ---- phaRep (wave0) + y1rep k-pad zero (wave1) ----
    if (wid == 0) {
        if (l < 48) {
            int py = (l * 43) >> 8, px = l - py * 6;
            *(f16x8*)&pool[l][8]  = z8;
            *(f16x8*)&pool[l][16] = z8;
            *(f16x8*)&pool[l][24] = z8;
#pragma unroll
            for (int t = 0; t < 9; t++) {
                int ky = t / 3, kx = t % 3;
                int ip = (py + ky) * 8 + px + kx;
                pool[l][t] = (_Float16)pha8[ip & 63];
            }
        }
    } else {
        for (int i = l; i < 144; i += 64) {
            int row = i >> 2, chunk = i & 3;
            *(f16x8*)&y1rep[row][72 + chunk * 8] = z8;
        }
    }
    __syncthreads();

    // ---- conv1: 33ch -> 24, 8x8 -> 6x6, MFMA ----
    f32x4 zf = {0.f, 0.f, 0.f, 0.f};
    f32x4 aA0 = zf, aA1 = zf, aB = zf;
    int nA = wid * 16 + lo, nB = 32 + lo;
    int pyA = (nA * 43) >> 8, pxA = nA - pyA * 6;
    int pyB = (nB * 43) >> 8, pxB = nB - pyB * 6;
    {   // pha K-tile (taps in k)
        f16x8 A0 = ldfrag(wf, 36, l), A1 = ldfrag(wf, 37, l);
        f16x8 BA = *(const f16x8*)&pool[nA][hi * 8];
        f16x8 BB = *(const f16x8*)&pool[nB][hi * 8];
        aA0 = MFMA16(A0, BA, aA0);
        aA1 = MFMA16(A1, BA, aA1);
        aB  = MFMA16(wid ? A1 : A0, BB, aB);
    }
#pragma unroll
    for (int ky = 0; ky < 3; ky++) {
#pragma unroll
        for (int kt = 0; kt < 3; kt++) {
            f16x8 A0 = ldfrag(wf, ky * 6 + kt * 2 + 0, l);
            f16x8 A1 = ldfrag(wf, ky * 6 + kt * 2 + 1, l);
            int rA = ((pyA + ky) * 8 + pxA + kt) & 63;   // identity for valid n (<36); wraps garbage
            int rB = ((pyB + ky) * 8 + pxB + kt) & 63;
            f16x8 BA = *(const f16x8*)&xs[rA][hi * 8];
            f16x8 BB = *(const f16x8*)&xs[rB][hi * 8];
            aA0 = MFMA16(A0, BA, aA0);
            aA1 = MFMA16(A1, BA, aA1);
            aB  = MFMA16(wid ? A1 : A0, BB, aB);
        }
    }
    // epilogue -> y1rep (bias+relu+f16, kx-replicated)
    {
        f32x4 accs[3] = {aA0, aA1, aB};
        int mts[3] = {0, 1, wid};
        int nts[3] = {wid, wid, 2};
#pragma unroll
        for (int f = 0; f < 3; f++) {
            int n = nts[f] * 16 + lo;
            int ocb = mts[f] * 16 + hi * 4;
            if (n < 36 && ocb < 24) {
                int py = (n * 43) >> 8, px = n - py * 6;
                f16x4 hh;
                hh[0] = (_Float16)fmaxf(accs[f][0] + biasL[ocb + 0], 0.f);
                hh[1] = (_Float16)fmaxf(accs[f][1] + biasL[ocb + 1], 0.f);
                hh[2] = (_Float16)fmaxf(accs[f][2] + biasL[ocb + 2], 0.f);
                hh[3] = (_Float16)fmaxf(accs[f][3] + biasL[ocb + 3], 0.f);
#pragma unroll
                for (int kx = 0; kx < 3; kx++) {
                    int px2 = px - kx;
                    if (px2 >= 0) *(f16x4*)&y1rep[py * 6 + px2][kx * 24 + ocb] = hh;
                }
            }
        }
    }
    __syncthreads();

    // ---- conv2 (wave0) : 24ch 6x6 -> 16ch 4x4 ; wave1 zeroes y2up pad ----
    if (wid == 0) {
        f32x4 a2 = zf;
        int qy = lo >> 2, qx = lo & 3;
#pragma unroll
        for (int ky = 0; ky < 3; ky++) {
#pragma unroll
            for (int kt = 0; kt < 3; kt++) {
                f16x8 A = ldfrag(wf, 18 + ky * 3 + kt, l);
                f16x8 B = *(const f16x8*)&y1rep[(qy + ky) * 6 + qx][kt * 32 + hi * 8];
                a2 = MFMA16(A, B, a2);
            }
        }
        int ocb = hi * 4;
        f16x4 hh;
        hh[0] = (_Float16)fmaxf(a2[0] + biasL[24 + ocb + 0], 0.f);
        hh[1] = (_Float16)fmaxf(a2[1] + biasL[24 + ocb + 1], 0.f);
        hh[2] = (_Float16)fmaxf(a2[2] + biasL[24 + ocb + 2], 0.f);
        hh[3] = (_Float16)fmaxf(a2[3] + biasL[24 + ocb + 3], 0.f);
#pragma unroll
        for (int dy = 0; dy < 2; dy++)
#pragma unroll
            for (int dx = 0; dx < 2; dx++) {
                int row = (2 * qy + dy) * 8 + 2 * qx + dx;
                *(f16x4*)&pool[row][ocb] = hh;     // y2up (nearest 2x)
            }
    } else {
        *(f16x8*)&pool[l][16] = z8;                // y2up k-pad 16..31
        *(f16x8*)&pool[l][24] = z8;
    }
    __syncthreads();

    // ---- conv3: 16ch 8x8 -> 12ch 6x6 ; wave0: nt0, wave1: nt1,nt2 ----
    f32x4 aC = zf, aD = zf;
    int nC = wid * 16 + lo, nD = 32 + lo;
    int pyC = (nC * 43) >> 8, pxC = nC - pyC * 6;
    int pyD = (nD * 43) >> 8, pxD = nD - pyD * 6;
#pragma unroll
    for (int s = 0; s < 9; s++) {
        int ky = s / 3, kx = s % 3;
        f16x8 A = ldfrag(wf, 27 + s, l);
        f16x8 BC = *(const f16x8*)&pool[((pyC + ky) * 8 + pxC + kx) & 63][hi * 8];
        aC = MFMA16(A, BC, aC);
        if (wid) {
            f16x8 BD = *(const f16x8*)&pool[((pyD + ky) * 8 + pxD + kx) & 63][hi * 8];
            aD = MFMA16(A, BD, aD);
        }
    }
    __syncthreads();   // y1rep reads done (conv2), safe to overwrite as y3s
    {
        int ocb = hi * 4;
        f32x4 accs[2] = {aC, aD};
        int nts[2] = {wid, 2};
        int cnt = wid ? 2 : 1;
        for (int f = 0; f < cnt; f++) {
            int n = nts[f] * 16 + lo;
            if (n < 36) {
                f32x4 v;
#pragma unroll
                for (int r = 0; r < 4; r++) {
                    float bb = (ocb + r < 12) ? biasL[40 + ocb + r] : 0.f;
                    float x = accs[f][r] + bb;
                    v[r] = (ocb + r < 12) ? fmaxf(x, 0.f) : 0.f;
                }
                *(f32x4*)&y3s[n * 16 + ocb] = v;
            }
        }
    }
    __syncthreads();

    // ---- conv4 (wave0): 12ch 6x6 -> 1ch 4x4, f32, + scatter store ----
    if (wid == 0) {
        int r4 = lo >> 2, c4 = lo & 3, cig = hi;
        float acc = 0.f;
#pragma unroll
        for (int t = 0; t < 9; t++) {
            int ky = t / 3, kx = t % 3;
            const f32x4 xv = *(const f32x4*)&y3s[((r4 + ky) * 6 + c4 + kx) * 16 + cig * 4];
            const f32x4 wv = *(const f32x4*)(w4r + t * 16 + cig * 4);
            acc += xv[0] * wv[0] + xv[1] * wv[1] + xv[2] * wv[2] + xv[3] * wv[3];
        }
        acc += __shfl_xor(acc, 32);
        acc += __shfl_xor(acc, 16);
        if (l < 16) {
            out[(size_t)b * 4194304 + (size_t)(hq * 4 + r4) * 2048 + (wq * 4 + c4)] = acc + biasL[52];
        }
    }
}

extern "C" void kernel_launch(void* const* d_in, const int* in_sizes, int n_in,
                              void* d_out, int out_size, void* d_ws, size_t ws_size,
                              hipStream_t stream) {
    const float* pha = (const float*)d_in[0];
    const float* err = (const float*)d_in[1];
    const float* hid = (const float*)d_in[2];
    const float* w1  = (const float*)d_in[3];
    const float* g1  = (const float*)d_in[4];
    const float* bb1 = (const float*)d_in[5];
    const float* m1  = (const float*)d_in[6];
    const float* v1  = (const float*)d_in[7];
    const float* w2  = (const float*)d_in[8];
    const float* g2  = (const float*)d_in[9];
    const float* bb2 = (const float*)d_in[10];
    const float* m2  = (const float*)d_in[11];
    const float* v2  = (const float*)d_in[12];
    const float* w3  = (const float*)d_in[13];
    const float* g3  = (const float*)d_in[14];
    const float* bb3 = (const float*)d_in[15];
    const float* m3  = (const float*)d_in[16];
    const float* v3  = (const float*)d_in[17];
    const float* w4  = (const float*)d_in[18];
    const float* b4  = (const float*)d_in[19];

    float* out    = (float*)d_out;
    float* refout = out + (size_t)NB * 4194304;
    char* ws      = (char*)d_ws;
    uint32_t* st  = (uint32_t*)(ws + ST_OFF);

    prep_kernel<<<1, 256, 0, stream>>>(w1, g1, bb1, m1, v1, w2, g2, bb2, m2, v2,
                                       w3, g3, bb3, m3, v3, w4, b4, ws);
    for (int r = 0; r < 4; r++) {
        hist_kernel<<<2048, 256, 0, stream>>>(err, st, r);
        scan_kernel<<<2, 64, 0, stream>>>(st, r);
    }
    compact_kernel<<<1024, 256, 0, stream>>>(err, st, refout);
    select_kernel<<<2, 256, 0, stream>>>(st, refout);
    upsample_kernel<<<8192, 256, 0, stream>>>(pha, out);
    patch_kernel<<<2 * K_SEL, 128, 0, stream>>>(hid, pha, ws, out);
}

// Round 10
// 166.333 us; speedup vs baseline: 4.0531x; 1.0182x over previous
//
#include <hip/hip_runtime.h>
#include <stdint.h>

#define K_SEL 5000
#define NQ    262144   // 512*512
#define NB    2

// ---------------- ws layout (bytes) ----------------
#define BIAS_OFF 38912
#define W4_OFF   39424
#define ST_OFF   40960

// ---------------- topk state (uint32 word offsets within st) ----------------
// [0..1] prefix  [2..3] rem  [4..5] T  [6..7] need  [8..9] selCount  [10..11] eqCount
// [16..2063] hist 4x2x256 ; [2064..12063] selList 2x5000 ; [12064..20255] eqList 2x4096
#define WS_HIST 16
#define WS_SEL  2064
#define WS_EQ   12064
#define EQ_CAP  4096

typedef _Float16 f16x8 __attribute__((ext_vector_type(8)));
typedef _Float16 f16x4 __attribute__((ext_vector_type(4)));
typedef float    f32x4 __attribute__((ext_vector_type(4)));
#define MFMA16(a,b,c) __builtin_amdgcn_mfma_f32_16x16x32_f16(a,b,c,0,0,0)

// ================= weight prep: fold BN, pack MFMA fragments, init topk state =================
__global__ void prep_kernel(const float* __restrict__ w1, const float* __restrict__ g1,
                            const float* __restrict__ b1, const float* __restrict__ m1,
                            const float* __restrict__ v1,
                            const float* __restrict__ w2, const float* __restrict__ g2,
                            const float* __restrict__ b2, const float* __restrict__ m2,
                            const float* __restrict__ v2,
                            const float* __restrict__ w3, const float* __restrict__ g3,
                            const float* __restrict__ b3, const float* __restrict__ m3,
                            const float* __restrict__ v3,
                            const float* __restrict__ w4, const float* __restrict__ b4,
                            char* __restrict__ ws) {
    _Float16* wf = (_Float16*)ws;
    float* bias = (float*)(ws + BIAS_OFF);
    float* w4r  = (float*)(ws + W4_OFF);
    uint32_t* st = (uint32_t*)(ws + ST_OFF);
    int tid = threadIdx.x;
    for (int t = tid; t < 38 * 512; t += 256) {
        int frag = t >> 9, li = (t >> 3) & 63, j = t & 7;
        int lo = li & 15, hi = li >> 4;
        float val = 0.f;
        if (frag < 18) {                                  // conv1: k = ci within fragment (ky,kx,mt)
            int ky = frag / 6, r = frag % 6, kx = r >> 1, mt = r & 1;
            int oc = mt * 16 + lo, ci = hi * 8 + j;
            if (oc < 24) val = w1[((oc * 33 + ci) * 3 + ky) * 3 + kx] * g1[oc] * rsqrtf(v1[oc] + 1e-5f);
        } else if (frag < 27) {                           // conv2: k = kx*24 + ci  (k<72)
            int f = frag - 18, ky = f / 3, kt = f % 3;
            int oc = lo, k = kt * 32 + hi * 8 + j;
            if (k < 72) {
                int kx = k / 24, ci = k % 24;
                val = w2[((oc * 24 + ci) * 3 + ky) * 3 + kx] * g2[oc] * rsqrtf(v2[oc] + 1e-5f);
            }
        } else if (frag < 36) {                           // conv3: k = ci (<16)
            int s = frag - 27, ky = s / 3, kx = s % 3;
            int oc = lo, ci = hi * 8 + j;
            if (oc < 12 && ci < 16) val = w3[((oc * 16 + ci) * 3 + ky) * 3 + kx] * g3[oc] * rsqrtf(v3[oc] + 1e-5f);
        } else {                                          // conv1 pha channel: k = tap (<9)
            int mt = frag - 36, oc = mt * 16 + lo, tap = hi * 8 + j;
            if (oc < 24 && tap < 9)
                val = w1[((oc * 33 + 32) * 3 + tap / 3) * 3 + tap % 3] * g1[oc] * rsqrtf(v1[oc] + 1e-5f);
        }
        wf[t] = (_Float16)val;
    }
    if (tid < 53) {
        float v;
        if (tid < 24)      { float sc = g1[tid] * rsqrtf(v1[tid] + 1e-5f); v = b1[tid] - m1[tid] * sc; }
        else if (tid < 40) { int c = tid - 24; float sc = g2[c] * rsqrtf(v2[c] + 1e-5f); v = b2[c] - m2[c] * sc; }
        else if (tid < 52) { int c = tid - 40; float sc = g3[c] * rsqrtf(v3[c] + 1e-5f); v = b3[c] - m3[c] * sc; }
        else v = b4[0];
        bias[tid] = v;
    }
    if (tid < 144) { int t9 = tid / 16, ci = tid % 16; w4r[tid] = (ci < 12) ? w4[ci * 9 + t9] : 0.f; }
    // topk state init
    for (int i = tid; i < WS_HIST + 4 * 512; i += 256) st[i] = 0u;
    __syncthreads();
    if (tid == 0) { st[2] = K_SEL; st[3] = K_SEL; }
}

// ================= top-k machinery =================
__global__ void hist_kernel(const float* __restrict__ err, uint32_t* st, int round) {
    __shared__ uint32_t h[256];
    h[threadIdx.x] = 0u;
    __syncthreads();
    int t = blockIdx.x * 256 + threadIdx.x;
    int b = t >> 18;
    uint32_t bits = __float_as_uint(err[t]);
    uint32_t pref = st[b];
    int shift = 24 - 8 * round;
    bool match = (round == 0) || ((bits >> (shift + 8)) == (pref >> (shift + 8)));
    if (match) atomicAdd(&h[(bits >> shift) & 255u], 1u);
    __syncthreads();
    uint32_t v = h[threadIdx.x];
    if (v) atomicAdd(&st[WS_HIST + round * 512 + b * 256 + threadIdx.x], v);
}

__global__ void scan_kernel(uint32_t* st, int round) {
    int b = blockIdx.x;
    int lane = threadIdx.x;
    int shift = 24 - 8 * round;
    const uint32_t* hist = st + WS_HIST + round * 512 + b * 256;
    int binbase = 255 - 4 * lane;
    uint32_t hv0 = hist[binbase], hv1 = hist[binbase - 1],
             hv2 = hist[binbase - 2], hv3 = hist[binbase - 3];
    uint32_t p = hv0 + hv1 + hv2 + hv3;
    uint32_t cum = p;
    for (int o = 1; o < 64; o <<= 1) {
        uint32_t n = __shfl_up(cum, o);
        if (lane >= o) cum += n;
    }
    uint32_t rem = st[2 + b];
    unsigned long long bal = __ballot(cum >= rem);
    int first = __ffsll(bal) - 1;
    if (lane == first) {
        uint32_t acc = cum - p;
        uint32_t hv[4] = {hv0, hv1, hv2, hv3};
        int chosen = binbase;
        for (int q = 0; q < 4; q++) {
            if (acc + hv[q] >= rem) { chosen = binbase - q; break; }
            acc += hv[q];
        }
        uint32_t pref = st[b] | ((uint32_t)chosen << shift);
        st[b] = pref;
        st[2 + b] = rem - acc;
        if (round == 3) { st[4 + b] = pref; st[6 + b] = rem - acc; }
    }
}

// compact + full refout write (replaces zero_ref). LDS-aggregated atomics.
__global__ void compact_kernel(const float* __restrict__ err, uint32_t* st,
                               float* __restrict__ refout) {
    __shared__ uint32_t selbuf[512];
    __shared__ uint32_t eqbuf[512];
    __shared__ uint32_t cnts[2];
    __shared__ uint32_t bases[2];
    int blk = blockIdx.x;                 // 1024 blocks; 512 per batch
    int b = blk >> 9;
    int base = (blk & 511) << 9;          // 512 elements per block
    if (threadIdx.x < 2) cnts[threadIdx.x] = 0u;
    __syncthreads();
    uint32_t T = st[4 + b];
#pragma unroll
    for (int it = 0; it < 2; it++) {
        int i = base + it * 256 + threadIdx.x;
        uint32_t bits = __float_as_uint(err[b * NQ + i]);
        float rv = 0.f;
        if (bits > T) {
            rv = 1.0f;
            uint32_t s = atomicAdd(&cnts[0], 1u);
            selbuf[s] = (uint32_t)i;
        } else if (bits == T) {
            uint32_t e = atomicAdd(&cnts[1], 1u);
            eqbuf[e] = (uint32_t)i;
        }
        refout[b * NQ + i] = rv;
    }
    __syncthreads();
    if (threadIdx.x == 0 && cnts[0]) bases[0] = atomicAdd(&st[8 + b], cnts[0]);
    if (threadIdx.x == 1 && cnts[1]) bases[1] = atomicAdd(&st[10 + b], cnts[1]);
    __syncthreads();
    for (uint32_t j = threadIdx.x; j < cnts[0]; j += 256) {
        uint32_t slot = bases[0] + j;
        if (slot < K_SEL) st[WS_SEL + b * K_SEL + slot] = selbuf[j];
    }
    for (uint32_t j = threadIdx.x; j < cnts[1]; j += 256) {
        uint32_t slot = bases[1] + j;
        if (slot < EQ_CAP) st[WS_EQ + b * EQ_CAP + slot] = eqbuf[j];
    }
}

__global__ void select_kernel(uint32_t* st, float* __restrict__ refout) {
    __shared__ uint32_t L[EQ_CAP];
    int b = blockIdx.x;
    uint32_t m = st[10 + b]; if (m > EQ_CAP) m = EQ_CAP;
    uint32_t need = st[6 + b];
    uint32_t T = st[4 + b];
    for (uint32_t j = threadIdx.x; j < m; j += blockDim.x) L[j] = st[WS_EQ + b * EQ_CAP + j];
    __syncthreads();
    for (uint32_t j = threadIdx.x; j < m; j += blockDim.x) {
        uint32_t idx = L[j];
        uint32_t rank = 0;
        for (uint32_t q = 0; q < m; q++) rank += (L[q] < idx) ? 1u : 0u;
        if (rank < need) {
            uint32_t slot = atomicAdd(&st[8 + b], 1u);
            if (slot < K_SEL) st[WS_SEL + b * K_SEL + slot] = idx;
            refout[b * NQ + idx] = (T != 0u) ? 1.0f : 0.0f;
        }
    }
}

// ================= 4x bilinear upsample of pha =================
__global__ void upsample_kernel(const float* __restrict__ pha, float* __restrict__ out) {
    int t = blockIdx.x * 256 + threadIdx.x;
    int xq = t & 511;
    int rest = t >> 9;
    int oy = rest & 2047;
    int b  = rest >> 11;
    const float* src = pha + (size_t)b * NQ;
    float sy = oy * 0.25f - 0.375f;
    sy = fminf(fmaxf(sy, 0.0f), 511.0f);
    int y0 = (int)sy; int y1i = min(y0 + 1, 511);
    float fy = sy - (float)y0;
    float rv[4];
#pragma unroll
    for (int j = 0; j < 4; j++) {
        int ox = xq * 4 + j;
        float sx = ox * 0.25f - 0.375f;
        sx = fminf(fmaxf(sx, 0.0f), 511.0f);
        int x0 = (int)sx; int x1i = min(x0 + 1, 511);
        float fx = sx - (float)x0;
        float v00 = src[y0 * 512 + x0],  v01 = src[y0 * 512 + x1i];
        float v10 = src[y1i * 512 + x0], v11 = src[y1i * 512 + x1i];
        rv[j] = v00 * (1.f - fy) * (1.f - fx) + v01 * (1.f - fy) * fx
              + v10 * fy * (1.f - fx)         + v11 * fy * fx;
    }
    float4 r4 = make_float4(rv[0], rv[1], rv[2], rv[3]);
    *reinterpret_cast<float4*>(out + (size_t)b * 4194304 + (size_t)oy * 2048 + xq * 4) = r4;
}

// ================= MFMA patch CNN: 2 waves / patch =================
// vs R8 (proven): y1rep[36][104] -> y1n[36][40], pool[64][56] -> pool[64][40]
// (same non-replicated transform class proven on xs in R8). LDS 20480 -> 13600.
__device__ __forceinline__ f16x8 ldfrag(const _Float16* wf, int frag, int l) {
    return *(const f16x8*)(wf + frag * 512 + l * 8);
}

__global__ __launch_bounds__(128) void patch_kernel(
    const float* __restrict__ hid, const float* __restrict__ pha,
    const char* __restrict__ ws, float* __restrict__ out) {
    __shared__ _Float16 xs[64][40];      // [8x8 pos][ci], ci 0..31 valid
    __shared__ _Float16 y1n[36][40];     // [6x6 pos][oc], oc 0..23 valid, 24..39 zero
    __shared__ _Float16 pool[64][40];    // phaP [48][40] (conv1) then y2u [64][40] (conv3)
    __shared__ float pha8[64];
    __shared__ float biasL[56];
    float* y3s = (float*)&y1n[0][0];     // [36][16] f32 = 2304B <= 2880B (dead after conv2)

    const _Float16* wf = (const _Float16*)ws;
    const float* biasG = (const float*)(ws + BIAS_OFF);
    const float* w4r   = (const float*)(ws + W4_OFF);
    const uint32_t* st = (const uint32_t*)(ws + ST_OFF);

    int tid = threadIdx.x, l = tid & 63, wid = tid >> 6;
    int lo = l & 15, hi = l >> 4;
    int bp = blockIdx.x;                 // no swizzle, no cooperative (both convicted)
    int b = (bp >= K_SEL) ? 1 : 0;
    int pi = bp - b * K_SEL;
    uint32_t idx = st[WS_SEL + b * K_SEL + pi] & 0x3FFFFu;   // clamp: fault-proof
    int hq = (int)(idx >> 9), wq = (int)(idx & 511u);

    if (tid < 53) biasL[tid] = biasG[tid];

    // ---- gather: lane = 8x8 position, wave = 16-channel half ----
    int ry = l >> 3, rx = l & 7;
    int hy = hq * 2 + ry - 3, hx = wq * 2 + rx - 3;
    bool inb = ((unsigned)hy < 1024u) && ((unsigned)hx < 1024u);
    float sy = fminf(fmaxf(hy * 0.5f - 0.25f, 0.f), 511.f);
    float sx = fminf(fmaxf(hx * 0.5f - 0.25f, 0.f), 511.f);
    int y0 = (int)sy, x0 = (int)sx;
    int y1c = min(y0 + 1, 511), x1c = min(x0 + 1, 511);
    float fy = sy - (float)y0, fx = sx - (float)x0;
    int o00 = y0 * 512 + x0, o01 = y0 * 512 + x1c, o10 = y1c * 512 + x0, o11 = y1c * 512 + x1c;
    float w00 = (1.f - fy) * (1.f - fx), w01 = (1.f - fy) * fx;
    float w10 = fy * (1.f - fx), w11 = fy * fx;

    _Float16 hv[16];
    {
        const float* hb = hid + ((size_t)b * 32 + wid * 16) * NQ;
#pragma unroll
        for (int c = 0; c < 16; c++) {
            const float* p = hb + (size_t)c * NQ;
            float v = 0.f;
            if (inb) v = p[o00] * w00 + p[o01] * w01 + p[o10] * w10 + p[o11] * w11;
            hv[c] = (_Float16)v;
        }
    }
    f16x8 h0 = {hv[0], hv[1], hv[2], hv[3], hv[4], hv[5], hv[6], hv[7]};
    f16x8 h1 = {hv[8], hv[9], hv[10], hv[11], hv[12], hv[13], hv[14], hv[15]};
    {
        _Float16* xrow = &xs[l][wid * 16];
        *(f16x8*)xrow = h0;
        *((f16x8*)xrow + 1) = h1;
    }
    f16x8 z8 = {(_Float16)0.f, (_Float16)0.f, (_Float16)0.f, (_Float16)0.f,
                (_Float16)0.f, (_Float16)0.f, (_Float16)0.f, (_Float16)0.f};
    if (wid == 1) {
        const float* p = pha + (size_t)b * NQ;
        float v = 0.f;
        if (inb) v = p[o00] * w00 + p[o01] * w01 + p[o10] * w10 + p[o11] * w11;
        pha8[l] = v;
    }
    __syncthreads();

    // ---- phaP build (wave0, rows 0..47) + y1n pad-col zero (wave1) ----
    if (wid == 0) {
        if (l < 48) {
            int py = (l * 43) >> 8, px = l - py * 6;
            _Float16 tap[9];
#pragma unroll
            for (int t = 0; t < 9; t++) {
                int ky = t / 3, kx = t % 3;
                int ip = (py + ky) * 8 + px + kx;
                tap[t] = (_Float16)pha8[ip & 63];
            }
            _Float16* row = &pool[l][0];
            f16x8 r0 = {tap[0], tap[1], tap[2], tap[3], tap[4], tap[5], tap[6], tap[7]};
            f16x8 r1 = z8; r1[0] = tap[8];
            *(f16x8*)row = r0;
            *(f16x8*)(row + 8)  = r1;
            *(f16x8*)(row + 16) = z8;
            *(f16x8*)(row + 24) = z8;      // cols 9..31 zero (32..39 never read)
        }
    } else {
        for (int i = l; i < 72; i += 64) {
            *(f16x8*)&y1n[i >> 1][24 + (i & 1) * 8] = z8;   // cols 24..39 of all 36 rows
        }
    }
    __syncthreads();

    // ---- conv1: 33ch -> 24, 8x8 -> 6x6, MFMA ----
    f32x4 zf = {0.f, 0.f, 0.f, 0.f};
    f32x4 aA0 = zf, aA1 = zf, aB = zf;
    int nA = wid * 16 + lo, nB = 32 + lo;
    int pyA = (nA * 43) >> 8, pxA = nA - pyA * 6;
    int pyB = (nB * 43) >> 8, pxB = nB - pyB * 6;
    {   // pha K-tile (taps in k)
        f16x8 A0 = ldfrag(wf, 36, l), A1 = ldfrag(wf, 37, l);
        f16x8 BA = *(const f16x8*)&pool[nA][hi * 8];
        f16x8 BB = *(const f16x8*)&pool[nB][hi * 8];
        aA0 = MFMA16(A0, BA, aA0);
        aA1 = MFMA16(A1, BA, aA1);
        aB  = MFMA16(wid ? A1 : A0, BB, aB);
    }
#pragma unroll
    for (int ky = 0; ky < 3; ky++) {
#pragma unroll
        for (int kt = 0; kt < 3; kt++) {
            f16x8 A0 = ldfrag(wf, ky * 6 + kt * 2 + 0, l);
            f16x8 A1 = ldfrag(wf, ky * 6 + kt * 2 + 1, l);
            int rA = ((pyA + ky) * 8 + pxA + kt) & 63;   // identity for valid n (<36); wraps garbage
            int rB = ((pyB + ky) * 8 + pxB + kt) & 63;
            f16x8 BA = *(const f16x8*)&xs[rA][hi * 8];
            f16x8 BB = *(const f16x8*)&xs[rB][hi * 8];
            aA0 = MFMA16(A0, BA, aA0);
            aA1 = MFMA16(A1, BA, aA1);
            aB  = MFMA16(wid ? A1 : A0, BB, aB);
        }
    }
    // epilogue -> y1n (bias+relu+f16, single write)
    {
        f32x4 accs[3] = {aA0, aA1, aB};
        int mts[3] = {0, 1, wid};
        int nts[3] = {wid, wid, 2};
#pragma unroll
        for (int f = 0; f < 3; f++) {
            int n = nts[f] * 16 + lo;
            int ocb = mts[f] * 16 + hi * 4;
            if (n < 36 && ocb < 24) {
                f16x4 hh;
                hh[0] = (_Float16)fmaxf(accs[f][0] + biasL[ocb + 0], 0.f);
                hh[1] = (_Float16)fmaxf(accs[f][1] + biasL[ocb + 1], 0.f);
                hh[2] = (_Float16)fmaxf(accs[f][2] + biasL[ocb + 2], 0.f);
                hh[3] = (_Float16)fmaxf(accs[f][3] + biasL[ocb + 3], 0.f);
                *(f16x4*)&y1n[n][ocb] = hh;
            }
        }
    }
    __syncthreads();

    // ---- conv2 (wave0): 24ch 6x6 -> 16ch 4x4 ; wave1 zeroes y2u pads ----
    if (wid == 0) {
        f32x4 a2 = zf;
        int qy = lo >> 2, qx = lo & 3;
#pragma unroll
        for (int ky = 0; ky < 3; ky++) {
#pragma unroll
            for (int kt = 0; kt < 3; kt++) {
                f16x8 A = ldfrag(wf, 18 + ky * 3 + kt, l);
                int k = kt * 32 + hi * 8;
                const _Float16* bptr;
                if (k < 72) {
                    int kx = k / 24, ci0 = k - kx * 24;
                    bptr = &y1n[(qy + ky) * 6 + qx + kx][ci0];
                } else {
                    bptr = &y1n[0][24];                   // zeroed pad
                }
                f16x8 B = *(const f16x8*)bptr;
                a2 = MFMA16(A, B, a2);
            }
        }
        int ocb = hi * 4;
        f16x4 hh;
        hh[0] = (_Float16)fmaxf(a2[0] + biasL[24 + ocb + 0], 0.f);
        hh[1] = (_Float16)fmaxf(a2[1] + biasL[24 + ocb + 1], 0.f);
        hh[2] = (_Float16)fmaxf(a2[2] + biasL[24 + ocb + 2], 0.f);
        hh[3] = (_Float16)fmaxf(a2[3] + biasL[24 + ocb + 3], 0.f);
#pragma unroll
        for (int dy = 0; dy < 2; dy++)
#pragma unroll
            for (int dx = 0; dx < 2; dx++) {
                int row = (2 * qy + dy) * 8 + 2 * qx + dx;
                *(f16x4*)&pool[row][ocb] = hh;            // y2u (nearest 2x)
            }
    } else {
        *(f16x8*)&pool[l][16] = z8;                       // y2u pad cols 16..31
        *(f16x8*)&pool[l][24] = z8;
    }
    __syncthreads();

    // ---- conv3: 16ch 8x8 -> 12ch 6x6 ; wave0: nt0, wave1: nt1,nt2 ----
    f32x4 aC = zf, aD = zf;
    int nC = wid * 16 + lo, nD = 32 + lo;
    int pyC = (nC * 43) >> 8, pxC = nC - pyC * 6;
    int pyD = (nD * 43) >> 8, pxD = nD - pyD * 6;
#pragma unroll
    for (int s = 0; s < 9; s++) {
        int ky = s / 3, kx = s % 3;
        f16x8 A = ldfrag(wf, 27 + s, l);
        f16x8 BC = *(const f16x8*)&pool[((pyC + ky) * 8 + pxC + kx) & 63][hi * 8];
        aC = MFMA16(A, BC, aC);
        if (wid) {
            f16x8 BD = *(const f16x8*)&pool[((pyD + ky) * 8 + pxD + kx) & 63][hi * 8];
            aD = MFMA16(A, BD, aD);
        }
    }
    __syncthreads();   // y1n reads done (conv2), safe to overwrite as y3s
    {
        int ocb = hi * 4;
        f32x4 accs[2] = {aC, aD};
        int nts[2] = {wid, 2};
        int cnt = wid ? 2 : 1;
        for (int f = 0; f < cnt; f++) {
            int n = nts[f] * 16 + lo;
            if (n < 36) {
                f32x4 v;
#pragma unroll
                for (int r = 0; r < 4; r++) {
                    float bb = (ocb + r < 12) ? biasL[40 + ocb + r] : 0.f;
                    float x = accs[f][r] + bb;
                    v[r] = (ocb + r < 12) ? fmaxf(x, 0.f) : 0.f;
                }
                *(f32x4*)&y3s[n * 16 + ocb] = v;
            }
        }
    }
    __syncthreads();

    // ---- conv4 (wave0): 12ch 6x6 -> 1ch 4x4, f32, + scatter store ----
    if (wid == 0) {
        int r4 = lo >> 2, c4 = lo & 3, cig = hi;
        float acc = 0.f;
#pragma unroll
        for (int t = 0; t < 9; t++) {
            int ky = t / 3, kx = t % 3;
            const f32x4 xv = *(const f32x4*)&y3s[((r4 + ky) * 6 + c4 + kx) * 16 + cig * 4];
            const f32x4 wv = *(const f32x4*)(w4r + t * 16 + cig * 4);
            acc += xv[0] * wv[0] + xv[1] * wv[1] + xv[2] * wv[2] + xv[3] * wv[3];
        }
        acc += __shfl_xor(acc, 32);
        acc += __shfl_xor(acc, 16);
        if (l < 16) {
            out[(size_t)b * 4194304 + (size_t)(hq * 4 + r4) * 2048 + (wq * 4 + c4)] = acc + biasL[52];
        }
    }
}

extern "C" void kernel_launch(void* const* d_in, const int* in_sizes, int n_in,
                              void* d_out, int out_size, void* d_ws, size_t ws_size,
                              hipStream_t stream) {
    const float* pha = (const float*)d_in[0];
    const float* err = (const float*)d_in[1];
    const float* hid = (const float*)d_in[2];
    const float* w1  = (const float*)d_in[3];
    const float* g1  = (const float*)d_in[4];
    const float* bb1 = (const float*)d_in[5];
    const float* m1  = (const float*)d_in[6];
    const float* v1  = (const float*)d_in[7];
    const float* w2  = (const float*)d_in[8];
    const float* g2  = (const float*)d_in[9];
    const float* bb2 = (const float*)d_in[10];
    const float* m2  = (const float*)d_in[11];
    const float* v2  = (const float*)d_in[12];
    const float* w3  = (const float*)d_in[13];
    const float* g3  = (const float*)d_in[14];
    const float* bb3 = (const float*)d_in[15];
    const float* m3  = (const float*)d_in[16];
    const float* v3  = (const float*)d_in[17];
    const float* w4  = (const float*)d_in[18];
    const float* b4  = (const float*)d_in[19];

    float* out    = (float*)d_out;
    float* refout = out + (size_t)NB * 4194304;
    char* ws      = (char*)d_ws;
    uint32_t* st  = (uint32_t*)(ws + ST_OFF);

    prep_kernel<<<1, 256, 0, stream>>>(w1, g1, bb1, m1, v1, w2, g2, bb2, m2, v2,
                                       w3, g3, bb3, m3, v3, w4, b4, ws);
    for (int r = 0; r < 4; r++) {
        hist_kernel<<<2048, 256, 0, stream>>>(err, st, r);
        scan_kernel<<<2, 64, 0, stream>>>(st, r);
    }
    compact_kernel<<<1024, 256, 0, stream>>>(err, st, refout);
    select_kernel<<<2, 256, 0, stream>>>(st, refout);
    upsample_kernel<<<8192, 256, 0, stream>>>(pha, out);
    patch_kernel<<<2 * K_SEL, 128, 0, stream>>>(hid, pha, ws, out);
}

// Round 11
// 158.732 us; speedup vs baseline: 4.2472x; 1.0479x over previous
//
#include <hip/hip_runtime.h>
#include <stdint.h>

#define K_SEL 5000
#define NQ    262144   // 512*512
#define NB    2

// ---------------- ws layout (bytes) ----------------
#define BIAS_OFF 38912
#define W4_OFF   39424
#define ST_OFF   40960

// ---------------- topk state (uint32 word offsets within st) ----------------
// [0..1] prefix  [2..3] rem  [4..5] T  [6..7] need  [8..9] selTotal  [10..11] eqCount
// [16..2063] hist 4x2x256 ; [2064..12063] selList 2x5000 ; [12064..20255] eqList 2x4096
// [20480..21503] per-block sel counts ; [21504..22527] per-block bases
#define WS_HIST  16
#define WS_SEL   2064
#define WS_EQ    12064
#define EQ_CAP   4096
#define WS_BCNT  20480
#define WS_BBASE 21504

typedef _Float16 f16x8 __attribute__((ext_vector_type(8)));
typedef _Float16 f16x4 __attribute__((ext_vector_type(4)));
typedef float    f32x4 __attribute__((ext_vector_type(4)));
#define MFMA16(a,b,c) __builtin_amdgcn_mfma_f32_16x16x32_f16(a,b,c,0,0,0)

// ================= weight prep: fold BN, pack MFMA fragments, init topk state =================
__global__ void prep_kernel(const float* __restrict__ w1, const float* __restrict__ g1,
                            const float* __restrict__ b1, const float* __restrict__ m1,
                            const float* __restrict__ v1,
                            const float* __restrict__ w2, const float* __restrict__ g2,
                            const float* __restrict__ b2, const float* __restrict__ m2,
                            const float* __restrict__ v2,
                            const float* __restrict__ w3, const float* __restrict__ g3,
                            const float* __restrict__ b3, const float* __restrict__ m3,
                            const float* __restrict__ v3,
                            const float* __restrict__ w4, const float* __restrict__ b4,
                            char* __restrict__ ws) {
    _Float16* wf = (_Float16*)ws;
    float* bias = (float*)(ws + BIAS_OFF);
    float* w4r  = (float*)(ws + W4_OFF);
    uint32_t* st = (uint32_t*)(ws + ST_OFF);
    int tid = threadIdx.x;
    for (int t = tid; t < 38 * 512; t += 256) {
        int frag = t >> 9, li = (t >> 3) & 63, j = t & 7;
        int lo = li & 15, hi = li >> 4;
        float val = 0.f;
        if (frag < 18) {                                  // conv1: k = ci within fragment (ky,kx,mt)
            int ky = frag / 6, r = frag % 6, kx = r >> 1, mt = r & 1;
            int oc = mt * 16 + lo, ci = hi * 8 + j;
            if (oc < 24) val = w1[((oc * 33 + ci) * 3 + ky) * 3 + kx] * g1[oc] * rsqrtf(v1[oc] + 1e-5f);
        } else if (frag < 27) {                           // conv2: k = kx*24 + ci  (k<72)
            int f = frag - 18, ky = f / 3, kt = f % 3;
            int oc = lo, k = kt * 32 + hi * 8 + j;
            if (k < 72) {
                int kx = k / 24, ci = k % 24;
                val = w2[((oc * 24 + ci) * 3 + ky) * 3 + kx] * g2[oc] * rsqrtf(v2[oc] + 1e-5f);
            }
        } else if (frag < 36) {                           // conv3: k = ci (<16)
            int s = frag - 27, ky = s / 3, kx = s % 3;
            int oc = lo, ci = hi * 8 + j;
            if (oc < 12 && ci < 16) val = w3[((oc * 16 + ci) * 3 + ky) * 3 + kx] * g3[oc] * rsqrtf(v3[oc] + 1e-5f);
        } else {                                          // conv1 pha channel: k = tap (<9)
            int mt = frag - 36, oc = mt * 16 + lo, tap = hi * 8 + j;
            if (oc < 24 && tap < 9)
                val = w1[((oc * 33 + 32) * 3 + tap / 3) * 3 + tap % 3] * g1[oc] * rsqrtf(v1[oc] + 1e-5f);
        }
        wf[t] = (_Float16)val;
    }
    if (tid < 53) {
        float v;
        if (tid < 24)      { float sc = g1[tid] * rsqrtf(v1[tid] + 1e-5f); v = b1[tid] - m1[tid] * sc; }
        else if (tid < 40) { int c = tid - 24; float sc = g2[c] * rsqrtf(v2[c] + 1e-5f); v = b2[c] - m2[c] * sc; }
        else if (tid < 52) { int c = tid - 40; float sc = g3[c] * rsqrtf(v3[c] + 1e-5f); v = b3[c] - m3[c] * sc; }
        else v = b4[0];
        bias[tid] = v;
    }
    if (tid < 144) { int t9 = tid / 16, ci = tid % 16; w4r[tid] = (ci < 12) ? w4[ci * 9 + t9] : 0.f; }
    // topk state init
    for (int i = tid; i < WS_HIST + 4 * 512; i += 256) st[i] = 0u;
    __syncthreads();
    if (tid == 0) { st[2] = K_SEL; st[3] = K_SEL; }
}

// ================= top-k machinery =================
__global__ void hist_kernel(const float* __restrict__ err, uint32_t* st, int round) {
    __shared__ uint32_t h[256];
    h[threadIdx.x] = 0u;
    __syncthreads();
    int t = blockIdx.x * 256 + threadIdx.x;
    int b = t >> 18;
    uint32_t bits = __float_as_uint(err[t]);
    uint32_t pref = st[b];
    int shift = 24 - 8 * round;
    bool match = (round == 0) || ((bits >> (shift + 8)) == (pref >> (shift + 8)));
    if (match) atomicAdd(&h[(bits >> shift) & 255u], 1u);
    __syncthreads();
    uint32_t v = h[threadIdx.x];
    if (v) atomicAdd(&st[WS_HIST + round * 512 + b * 256 + threadIdx.x], v);
}

__global__ void scan_kernel(uint32_t* st, int round) {
    int b = blockIdx.x;
    int lane = threadIdx.x;
    int shift = 24 - 8 * round;
    const uint32_t* hist = st + WS_HIST + round * 512 + b * 256;
    int binbase = 255 - 4 * lane;
    uint32_t hv0 = hist[binbase], hv1 = hist[binbase - 1],
             hv2 = hist[binbase - 2], hv3 = hist[binbase - 3];
    uint32_t p = hv0 + hv1 + hv2 + hv3;
    uint32_t cum = p;
    for (int o = 1; o < 64; o <<= 1) {
        uint32_t n = __shfl_up(cum, o);
        if (lane >= o) cum += n;
    }
    uint32_t rem = st[2 + b];
    unsigned long long bal = __ballot(cum >= rem);
    int first = __ffsll(bal) - 1;
    if (lane == first) {
        uint32_t acc = cum - p;
        uint32_t hv[4] = {hv0, hv1, hv2, hv3};
        int chosen = binbase;
        for (int q = 0; q < 4; q++) {
            if (acc + hv[q] >= rem) { chosen = binbase - q; break; }
            acc += hv[q];
        }
        uint32_t pref = st[b] | ((uint32_t)chosen << shift);
        st[b] = pref;
        st[2 + b] = rem - acc;
        if (round == 3) { st[4 + b] = pref; st[6 + b] = rem - acc; }
    }
}

// ---- deterministic sorted compact: count -> scan -> place ----
__global__ void ccount_kernel(const float* __restrict__ err, uint32_t* st) {
    __shared__ uint32_t wsum[8];
    int blk = blockIdx.x, tid = threadIdx.x;
    int b = blk >> 9, base = (blk & 511) << 9;
    uint32_t T = st[4 + b];
    uint32_t b0 = __float_as_uint(err[b * NQ + base + tid]);
    uint32_t b1 = __float_as_uint(err[b * NQ + base + 256 + tid]);
    unsigned long long m0 = __ballot(b0 > T);
    unsigned long long m1 = __ballot(b1 > T);
    int w = tid >> 6, lane = tid & 63;
    if (lane == 0) { wsum[w] = (uint32_t)__popcll(m0); wsum[4 + w] = (uint32_t)__popcll(m1); }
    __syncthreads();
    if (tid == 0)
        st[WS_BCNT + blk] = wsum[0] + wsum[1] + wsum[2] + wsum[3]
                          + wsum[4] + wsum[5] + wsum[6] + wsum[7];
}

__global__ void cscan_kernel(uint32_t* st) {      // 2 blocks x 512
    __shared__ uint32_t wtot[8];
    int b = blockIdx.x, tid = threadIdx.x;
    int lane = tid & 63, w = tid >> 6;
    uint32_t v = st[WS_BCNT + b * 512 + tid];
    uint32_t inc = v;
    for (int o = 1; o < 64; o <<= 1) {
        uint32_t n = __shfl_up(inc, o);
        if (lane >= o) inc += n;
    }
    if (lane == 63) wtot[w] = inc;
    __syncthreads();
    uint32_t off = 0;
    for (int j = 0; j < w; j++) off += wtot[j];
    uint32_t base = off + inc - v;
    st[WS_BBASE + b * 512 + tid] = base;
    if (tid == 511) st[8 + b] = base + v;         // selTotal (ties appended after)
}

__global__ void cplace_kernel(const float* __restrict__ err, uint32_t* st,
                              float* __restrict__ refout) {
    __shared__ uint32_t wc[8];
    int blk = blockIdx.x, tid = threadIdx.x;
    int b = blk >> 9, base = (blk & 511) << 9;
    uint32_t T = st[4 + b];
    uint32_t blkbase = st[WS_BBASE + b * 512 + (blk & 511)];
    int i0 = base + tid, i1 = base + 256 + tid;
    uint32_t b0 = __float_as_uint(err[b * NQ + i0]);
    uint32_t b1 = __float_as_uint(err[b * NQ + i1]);
    bool s0 = b0 > T, s1 = b1 > T;
    unsigned long long m0 = __ballot(s0);
    unsigned long long m1 = __ballot(s1);
    int w = tid >> 6, lane = tid & 63;
    if (lane == 0) { wc[w] = (uint32_t)__popcll(m0); wc[4 + w] = (uint32_t)__popcll(m1); }
    refout[b * NQ + i0] = s0 ? 1.0f : 0.0f;
    refout[b * NQ + i1] = s1 ? 1.0f : 0.0f;
    __syncthreads();
    uint32_t tot0 = wc[0] + wc[1] + wc[2] + wc[3];
    uint32_t pre0 = 0, pre1 = tot0;
    for (int j = 0; j < w; j++) { pre0 += wc[j]; pre1 += wc[4 + j]; }
    unsigned long long lt = (1ull << lane) - 1ull;
    if (s0) {
        uint32_t slot = blkbase + pre0 + (uint32_t)__popcll(m0 & lt);
        if (slot < K_SEL) st[WS_SEL + b * K_SEL + slot] = (uint32_t)i0;
    }
    if (s1) {
        uint32_t slot = blkbase + pre1 + (uint32_t)__popcll(m1 & lt);
        if (slot < K_SEL) st[WS_SEL + b * K_SEL + slot] = (uint32_t)i1;
    }
    if (b0 == T) { uint32_t e = atomicAdd(&st[10 + b], 1u); if (e < EQ_CAP) st[WS_EQ + b * EQ_CAP + e] = (uint32_t)i0; }
    if (b1 == T) { uint32_t e = atomicAdd(&st[10 + b], 1u); if (e < EQ_CAP) st[WS_EQ + b * EQ_CAP + e] = (uint32_t)i1; }
}

__global__ void select_kernel(uint32_t* st, float* __restrict__ refout) {
    __shared__ uint32_t L[EQ_CAP];
    int b = blockIdx.x;
    uint32_t m = st[10 + b]; if (m > EQ_CAP) m = EQ_CAP;
    uint32_t need = st[6 + b];
    uint32_t T = st[4 + b];
    for (uint32_t j = threadIdx.x; j < m; j += blockDim.x) L[j] = st[WS_EQ + b * EQ_CAP + j];
    __syncthreads();
    for (uint32_t j = threadIdx.x; j < m; j += blockDim.x) {
        uint32_t idx = L[j];
        uint32_t rank = 0;
        for (uint32_t q = 0; q < m; q++) rank += (L[q] < idx) ? 1u : 0u;
        if (rank < need) {
            uint32_t slot = atomicAdd(&st[8 + b], 1u);
            if (slot < K_SEL) st[WS_SEL + b * K_SEL + slot] = idx;
            refout[b * NQ + idx] = (T != 0u) ? 1.0f : 0.0f;
        }
    }
}

// ================= 4x bilinear upsample of pha =================
__global__ void upsample_kernel(const float* __restrict__ pha, float* __restrict__ out) {
    int t = blockIdx.x * 256 + threadIdx.x;
    int xq = t & 511;
    int rest = t >> 9;
    int oy = rest & 2047;
    int b  = rest >> 11;
    const float* src = pha + (size_t)b * NQ;
    float sy = oy * 0.25f - 0.375f;
    sy = fminf(fmaxf(sy, 0.0f), 511.0f);
    int y0 = (int)sy; int y1i = min(y0 + 1, 511);
    float fy = sy - (float)y0;
    float rv[4];
#pragma unroll
    for (int j = 0; j < 4; j++) {
        int ox = xq * 4 + j;
        float sx = ox * 0.25f - 0.375f;
        sx = fminf(fmaxf(sx, 0.0f), 511.0f);
        int x0 = (int)sx; int x1i = min(x0 + 1, 511);
        float fx = sx - (float)x0;
        float v00 = src[y0 * 512 + x0],  v01 = src[y0 * 512 + x1i];
        float v10 = src[y1i * 512 + x0], v11 = src[y1i * 512 + x1i];
        rv[j] = v00 * (1.f - fy) * (1.f - fx) + v01 * (1.f - fy) * fx
              + v10 * fy * (1.f - fx)         + v11 * fy * fx;
    }
    float4 r4 = make_float4(rv[0], rv[1], rv[2], rv[3]);
    *reinterpret_cast<float4*>(out + (size_t)b * 4194304 + (size_t)oy * 2048 + xq * 4) = r4;
}

// ================= MFMA patch CNN: 2 waves / patch (R10 proven, unchanged) =================
__device__ __forceinline__ f16x8 ldfrag(const _Float16* wf, int frag, int l) {
    return *(const f16x8*)(wf + frag * 512 + l * 8);
}

__global__ __launch_bounds__(128) void patch_kernel(
    const float* __restrict__ hid, const float* __restrict__ pha,
    const char* __restrict__ ws, float* __restrict__ out) {
    __shared__ _Float16 xs[64][40];      // [8x8 pos][ci], ci 0..31 valid
    __shared__ _Float16 y1n[36][40];     // [6x6 pos][oc], oc 0..23 valid, 24..39 zero
    __shared__ _Float16 pool[64][40];    // phaP [48][40] (conv1) then y2u [64][40] (conv3)
    __shared__ float pha8[64];
    __shared__ float biasL[56];
    float* y3s = (float*)&y1n[0][0];     // [36][16] f32 = 2304B <= 2880B (dead after conv2)

    const _Float16* wf = (const _Float16*)ws;
    const float* biasG = (const float*)(ws + BIAS_OFF);
    const float* w4r   = (const float*)(ws + W4_OFF);
    const uint32_t* st = (const uint32_t*)(ws + ST_OFF);

    int tid = threadIdx.x, l = tid & 63, wid = tid >> 6;
    int lo = l & 15, hi = l >> 4;
    int bp = blockIdx.x;
    int b = (bp >= K_SEL) ? 1 : 0;
    int pi = bp - b * K_SEL;
    uint32_t idx = st[WS_SEL + b * K_SEL + pi] & 0x3FFFFu;   // clamp: fault-proof
    int hq = (int)(idx >> 9), wq = (int)(idx & 511u);

    if (tid < 53) biasL[tid] = biasG[tid];

    // ---- gather: lane = 8x8 position, wave = 16-channel half ----
    int ry = l >> 3, rx = l & 7;
    int hy = hq * 2 + ry - 3, hx = wq * 2 + rx - 3;
    bool inb = ((unsigned)hy < 1024u) && ((unsigned)hx < 1024u);
    float sy = fminf(fmaxf(hy * 0.5f - 0.25f, 0.f), 511.f);
    float sx = fminf(fmaxf(hx * 0.5f - 0.25f, 0.f), 511.f);
    int y0 = (int)sy, x0 = (int)sx;
    int y1c = min(y0 + 1, 511), x1c = min(x0 + 1, 511);
    float fy = sy - (float)y0, fx = sx - (float)x0;
    int o00 = y0 * 512 + x0, o01 = y0 * 512 + x1c, o10 = y1c * 512 + x0, o11 = y1c * 512 + x1c;
    float w00 = (1.f - fy) * (1.f - fx), w01 = (1.f - fy) * fx;
    float w10 = fy * (1.f - fx), w11 = fy * fx;

    _Float16 hv[16];
    {
        const float* hb = hid + ((size_t)b * 32 + wid * 16) * NQ;
#pragma unroll
        for (int c = 0; c < 16; c++) {
            const float* p = hb + (size_t)c * NQ;
            float v = 0.f;
            if (inb) v = p[o00] * w00 + p[o01] * w01 + p[o10] * w10 + p[o11] * w11;
            hv[c] = (_Float16)v;
        }
    }
    f16x8 h0 = {hv[0], hv[1], hv[2], hv[3], hv[4], hv[5], hv[6], hv[7]};
    f16x8 h1 = {hv[8], hv[9], hv[10], hv[11], hv[12], hv[13], hv[14], hv[15]};
    {
        _Float16* xrow = &xs[l][wid * 16];
        *(f16x8*)xrow = h0;
        *((f16x8*)xrow + 1) = h1;
    }
    f16x8 z8 = {(_Float16)0.f, (_Float16)0.f, (_Float16)0.f, (_Float16)0.f,
                (_Float16)0.f, (_Float16)0.f, (_Float16)0.f, (_Float16)0.f};
    if (wid == 1) {
        const float* p = pha + (size_t)b * NQ;
        float v = 0.f;
        if (inb) v = p[o00] * w00 + p[o01] * w01 + p[o10] * w10 + p[o11] * w11;
        pha8[l] = v;
    }
    __syncthreads();

    // ---- phaP build (wave0, rows 0..47) + y1n pad-col zero (wave1) ----
    if (wid == 0) {
        if (l < 48) {
            int py = (l * 43) >> 8, px = l - py * 6;
            _Float16 tap[9];
#pragma unroll
            for (int t = 0; t < 9; t++) {
                int ky = t / 3, kx = t % 3;
                int ip = (py + ky) * 8 + px + kx;
                tap[t] = (_Float16)pha8[ip & 63];
            }
            _Float16* row = &pool[l][0];
            f16x8 r0 = {tap[0], tap[1], tap[2], tap[3], tap[4], tap[5], tap[6], tap[7]};
            f16x8 r1 = z8; r1[0] = tap[8];
            *(f16x8*)row = r0;
            *(f16x8*)(row + 8)  = r1;
            *(f16x8*)(row + 16) = z8;
            *(f16x8*)(row + 24) = z8;      // cols 9..31 zero (32..39 never read)
        }
    } else {
        for (int i = l; i < 72; i += 64) {
            *(f16x8*)&y1n[i >> 1][24 + (i & 1) * 8] = z8;   // cols 24..39 of all 36 rows
        }
    }
    __syncthreads();

    // ---- conv1: 33ch -> 24, 8x8 -> 6x6, MFMA ----
    f32x4 zf = {0.f, 0.f, 0.f, 0.f};
    f32x4 aA0 = zf, aA1 = zf, aB = zf;
    int nA = wid * 16 + lo, nB = 32 + lo;
    int pyA = (nA * 43) >> 8, pxA = nA - pyA * 6;
    int pyB = (nB * 43) >> 8, pxB = nB - pyB * 6;
    {   // pha K-tile (taps in k)
        f16x8 A0 = ldfrag(wf, 36, l), A1 = ldfrag(wf, 37, l);
        f16x8 BA = *(const f16x8*)&pool[nA][hi * 8];
        f16x8 BB = *(const f16x8*)&pool[nB][hi * 8];
        aA0 = MFMA16(A0, BA, aA0);
        aA1 = MFMA16(A1, BA, aA1);
        aB  = MFMA16(wid ? A1 : A0, BB, aB);
    }
#pragma unroll
    for (int ky = 0; ky < 3; ky++) {
#pragma unroll
        for (int kt = 0; kt < 3; kt++) {
            f16x8 A0 = ldfrag(wf, ky * 6 + kt * 2 + 0, l);
            f16x8 A1 = ldfrag(wf, ky * 6 + kt * 2 + 1, l);
            int rA = ((pyA + ky) * 8 + pxA + kt) & 63;   // identity for valid n (<36); wraps garbage
            int rB = ((pyB + ky) * 8 + pxB + kt) & 63;
            f16x8 BA = *(const f16x8*)&xs[rA][hi * 8];
            f16x8 BB = *(const f16x8*)&xs[rB][hi * 8];
            aA0 = MFMA16(A0, BA, aA0);
            aA1 = MFMA16(A1, BA, aA1);
            aB  = MFMA16(wid ? A1 : A0, BB, aB);
        }
    }
    // epilogue -> y1n (bias+relu+f16, single write)
    {
        f32x4 accs[3] = {aA0, aA1, aB};
        int mts[3] = {0, 1, wid};
        int nts[3] = {wid, wid, 2};
#pragma unroll
        for (int f = 0; f < 3; f++) {
            int n = nts[f] * 16 + lo;
            int ocb = mts[f] * 16 + hi * 4;
            if (n < 36 && ocb < 24) {
                f16x4 hh;
                hh[0] = (_Float16)fmaxf(accs[f][0] + biasL[ocb + 0], 0.f);
                hh[1] = (_Float16)fmaxf(accs[f][1] + biasL[ocb + 1], 0.f);
                hh[2] = (_Float16)fmaxf(accs[f][2] + biasL[ocb + 2], 0.f);
                hh[3] = (_Float16)fmaxf(accs[f][3] + biasL[ocb + 3], 0.f);
                *(f16x4*)&y1n[n][ocb] = hh;
            }
        }
    }
    __syncthreads();

    // ---- conv2 (wave0): 24ch 6x6 -> 16ch 4x4 ; wave1 zeroes y2u pads ----
    if (wid == 0) {
        f32x4 a2 = zf;
        int qy = lo >> 2, qx = lo & 3;
#pragma unroll
        for (int ky = 0; ky < 3; ky++) {
#pragma unroll
            for (int kt = 0; kt < 3; kt++) {
                f16x8 A = ldfrag(wf, 18 + ky * 3 + kt, l);
                int k = kt * 32 + hi * 8;
                const _Float16* bptr;
                if (k < 72) {
                    int kx = k / 24, ci0 = k - kx * 24;
                    bptr = &y1n[(qy + ky) * 6 + qx + kx][ci0];
                } else {
                    bptr = &y1n[0][24];                   // zeroed pad
                }
                f16x8 B = *(const f16x8*)bptr;
                a2 = MFMA16(A, B, a2);
            }
        }
        int ocb = hi * 4;
        f16x4 hh;
        hh[0] = (_Float16)fmaxf(a2[0] + biasL[24 + ocb + 0], 0.f);
        hh[1] = (_Float16)fmaxf(a2[1] + biasL[24 + ocb + 1], 0.f);
        hh[2] = (_Float16)fmaxf(a2[2] + biasL[24 + ocb + 2], 0.f);
        hh[3] = (_Float16)fmaxf(a2[3] + biasL[24 + ocb + 3], 0.f);
#pragma unroll
        for (int dy = 0; dy < 2; dy++)
#pragma unroll
            for (int dx = 0; dx < 2; dx++) {
                int row = (2 * qy + dy) * 8 + 2 * qx + dx;
                *(f16x4*)&pool[row][ocb] = hh;            // y2u (nearest 2x)
            }
    } else {
        *(f16x8*)&pool[l][16] = z8;                       // y2u pad cols 16..31
        *(f16x8*)&pool[l][24] = z8;
    }
    __syncthreads();

    // ---- conv3: 16ch 8x8 -> 12ch 6x6 ; wave0: nt0, wave1: nt1,nt2 ----
    f32x4 aC = zf, aD = zf;
    int nC = wid * 16 + lo, nD = 32 + lo;
    int pyC = (nC * 43) >> 8, pxC = nC - pyC * 6;
    int pyD = (nD * 43) >> 8, pxD = nD - pyD * 6;
#pragma unroll
    for (int s = 0; s < 9; s++) {
        int ky = s / 3, kx = s % 3;
        f16x8 A = ldfrag(wf, 27 + s, l);
        f16x8 BC = *(const f16x8*)&pool[((pyC + ky) * 8 + pxC + kx) & 63][hi * 8];
        aC = MFMA16(A, BC, aC);
        if (wid) {
            f16x8 BD = *(const f16x8*)&pool[((pyD + ky) * 8 + pxD + kx) & 63][hi * 8];
            aD = MFMA16(A, BD, aD);
        }
    }
    __syncthreads();   // y1n reads done (conv2), safe to overwrite as y3s
    {
        int ocb = hi * 4;
        f32x4 accs[2] = {aC, aD};
        int nts[2] = {wid, 2};
        int cnt = wid ? 2 : 1;
        for (int f = 0; f < cnt; f++) {
            int n = nts[f] * 16 + lo;
            if (n < 36) {
                f32x4 v;
#pragma unroll
                for (int r = 0; r < 4; r++) {
                    float bb = (ocb + r < 12) ? biasL[40 + ocb + r] : 0.f;
                    float x = accs[f][r] + bb;
                    v[r] = (ocb + r < 12) ? fmaxf(x, 0.f) : 0.f;
                }
                *(f32x4*)&y3s[n * 16 + ocb] = v;
            }
        }
    }
    __syncthreads();

    // ---- conv4 (wave0): 12ch 6x6 -> 1ch 4x4, f32, + scatter store ----
    if (wid == 0) {
        int r4 = lo >> 2, c4 = lo & 3, cig = hi;
        float acc = 0.f;
#pragma unroll
        for (int t = 0; t < 9; t++) {
            int ky = t / 3, kx = t % 3;
            const f32x4 xv = *(const f32x4*)&y3s[((r4 + ky) * 6 + c4 + kx) * 16 + cig * 4];
            const f32x4 wv = *(const f32x4*)(w4r + t * 16 + cig * 4);
            acc += xv[0] * wv[0] + xv[1] * wv[1] + xv[2] * wv[2] + xv[3] * wv[3];
        }
        acc += __shfl_xor(acc, 32);
        acc += __shfl_xor(acc, 16);
        if (l < 16) {
            out[(size_t)b * 4194304 + (size_t)(hq * 4 + r4) * 2048 + (wq * 4 + c4)] = acc + biasL[52];
        }
    }
}

extern "C" void kernel_launch(void* const* d_in, const int* in_sizes, int n_in,
                              void* d_out, int out_size, void* d_ws, size_t ws_size,
                              hipStream_t stream) {
    const float* pha = (const float*)d_in[0];
    const float* err = (const float*)d_in[1];
    const float* hid = (const float*)d_in[2];
    const float* w1  = (const float*)d_in[3];
    const float* g1  = (const float*)d_in[4];
    const float* bb1 = (const float*)d_in[5];
    const float* m1  = (const float*)d_in[6];
    const float* v1  = (const float*)d_in[7];
    const float* w2  = (const float*)d_in[8];
    const float* g2  = (const float*)d_in[9];
    const float* bb2 = (const float*)d_in[10];
    const float* m2  = (const float*)d_in[11];
    const float* v2  = (const float*)d_in[12];
    const float* w3  = (const float*)d_in[13];
    const float* g3  = (const float*)d_in[14];
    const float* bb3 = (const float*)d_in[15];
    const float* m3  = (const float*)d_in[16];
    const float* v3  = (const float*)d_in[17];
    const float* w4  = (const float*)d_in[18];
    const float* b4  = (const float*)d_in[19];

    float* out    = (float*)d_out;
    float* refout = out + (size_t)NB * 4194304;
    char* ws      = (char*)d_ws;
    uint32_t* st  = (uint32_t*)(ws + ST_OFF);

    prep_kernel<<<1, 256, 0, stream>>>(w1, g1, bb1, m1, v1, w2, g2, bb2, m2, v2,
                                       w3, g3, bb3, m3, v3, w4, b4, ws);
    for (int r = 0; r < 4; r++) {
        hist_kernel<<<2048, 256, 0, stream>>>(err, st, r);
        scan_kernel<<<2, 64, 0, stream>>>(st, r);
    }
    ccount_kernel<<<1024, 256, 0, stream>>>(err, st);
    cscan_kernel<<<2, 512, 0, stream>>>(st);
    cplace_kernel<<<1024, 256, 0, stream>>>(err, st, refout);
    select_kernel<<<2, 256, 0, stream>>>(st, refout);
    upsample_kernel<<<8192, 256, 0, stream>>>(pha, out);
    patch_kernel<<<2 * K_SEL, 128, 0, stream>>>(hid, pha, ws, out);
}

// Round 12
// 156.316 us; speedup vs baseline: 4.3128x; 1.0154x over previous
//
#include <hip/hip_runtime.h>
#include <stdint.h>

#define K_SEL 5000
#define NQ    262144   // 512*512
#define NB    2

// ---------------- ws layout (bytes) ----------------
#define BIAS_OFF 38912
#define W4_OFF   39424
#define ST_OFF   40960
#define XT_OFF   131072                      // channels-last f16 buffer
#define XT_BYTES ((size_t)NB * NQ * 40 * 2)  // 41,943,040
#define WS_NEED  (XT_OFF + XT_BYTES)

// ---------------- topk state (uint32 word offsets within st) ----------------
// [0..1] prefix  [2..3] rem  [4..5] T  [6..7] need  [8..9] selTotal  [10..11] eqCount
// [16..2063] hist 4x2x256 ; [2064..12063] selList 2x5000 ; [12064..20255] eqList 2x4096
// [20480..21503] per-block sel counts ; [21504..22527] per-block bases
#define WS_HIST  16
#define WS_SEL   2064
#define WS_EQ    12064
#define EQ_CAP   4096
#define WS_BCNT  20480
#define WS_BBASE 21504

typedef _Float16 f16x8 __attribute__((ext_vector_type(8)));
typedef _Float16 f16x4 __attribute__((ext_vector_type(4)));
typedef float    f32x4 __attribute__((ext_vector_type(4)));
#define MFMA16(a,b,c) __builtin_amdgcn_mfma_f32_16x16x32_f16(a,b,c,0,0,0)

// ================= weight prep: fold BN, pack MFMA fragments, init topk state =================
__global__ void prep_kernel(const float* __restrict__ w1, const float* __restrict__ g1,
                            const float* __restrict__ b1, const float* __restrict__ m1,
                            const float* __restrict__ v1,
                            const float* __restrict__ w2, const float* __restrict__ g2,
                            const float* __restrict__ b2, const float* __restrict__ m2,
                            const float* __restrict__ v2,
                            const float* __restrict__ w3, const float* __restrict__ g3,
                            const float* __restrict__ b3, const float* __restrict__ m3,
                            const float* __restrict__ v3,
                            const float* __restrict__ w4, const float* __restrict__ b4,
                            char* __restrict__ ws) {
    _Float16* wf = (_Float16*)ws;
    float* bias = (float*)(ws + BIAS_OFF);
    float* w4r  = (float*)(ws + W4_OFF);
    uint32_t* st = (uint32_t*)(ws + ST_OFF);
    int tid = threadIdx.x;
    for (int t = tid; t < 38 * 512; t += 256) {
        int frag = t >> 9, li = (t >> 3) & 63, j = t & 7;
        int lo = li & 15, hi = li >> 4;
        float val = 0.f;
        if (frag < 18) {                                  // conv1: k = ci within fragment (ky,kx,mt)
            int ky = frag / 6, r = frag % 6, kx = r >> 1, mt = r & 1;
            int oc = mt * 16 + lo, ci = hi * 8 + j;
            if (oc < 24) val = w1[((oc * 33 + ci) * 3 + ky) * 3 + kx] * g1[oc] * rsqrtf(v1[oc] + 1e-5f);
        } else if (frag < 27) {                           // conv2: k = kx*24 + ci  (k<72)
            int f = frag - 18, ky = f / 3, kt = f % 3;
            int oc = lo, k = kt * 32 + hi * 8 + j;
            if (k < 72) {
                int kx = k / 24, ci = k % 24;
                val = w2[((oc * 24 + ci) * 3 + ky) * 3 + kx] * g2[oc] * rsqrtf(v2[oc] + 1e-5f);
            }
        } else if (frag < 36) {                           // conv3: k = ci (<16)
            int s = frag - 27, ky = s / 3, kx = s % 3;
            int oc = lo, ci = hi * 8 + j;
            if (oc < 12 && ci < 16) val = w3[((oc * 16 + ci) * 3 + ky) * 3 + kx] * g3[oc] * rsqrtf(v3[oc] + 1e-5f);
        } else {                                          // conv1 pha channel: k = tap (<9)
            int mt = frag - 36, oc = mt * 16 + lo, tap = hi * 8 + j;
            if (oc < 24 && tap < 9)
                val = w1[((oc * 33 + 32) * 3 + tap / 3) * 3 + tap % 3] * g1[oc] * rsqrtf(v1[oc] + 1e-5f);
        }
        wf[t] = (_Float16)val;
    }
    if (tid < 53) {
        float v;
        if (tid < 24)      { float sc = g1[tid] * rsqrtf(v1[tid] + 1e-5f); v = b1[tid] - m1[tid] * sc; }
        else if (tid < 40) { int c = tid - 24; float sc = g2[c] * rsqrtf(v2[c] + 1e-5f); v = b2[c] - m2[c] * sc; }
        else if (tid < 52) { int c = tid - 40; float sc = g3[c] * rsqrtf(v3[c] + 1e-5f); v = b3[c] - m3[c] * sc; }
        else v = b4[0];
        bias[tid] = v;
    }
    if (tid < 144) { int t9 = tid / 16, ci = tid % 16; w4r[tid] = (ci < 12) ? w4[ci * 9 + t9] : 0.f; }
    // topk state init
    for (int i = tid; i < WS_HIST + 4 * 512; i += 256) st[i] = 0u;
    __syncthreads();
    if (tid == 0) { st[2] = K_SEL; st[3] = K_SEL; }
}

// ================= channels-last f16 transpose: xt[b][y][x][40] =================
__global__ void transpose_kernel(const float* __restrict__ hid, const float* __restrict__ pha,
                                 _Float16* __restrict__ xt) {
    int t = blockIdx.x * 256 + threadIdx.x;   // 524288 total
    int b = t >> 18, i = t & (NQ - 1);
    _Float16 v[40];
#pragma unroll
    for (int c = 0; c < 32; c++)
        v[c] = (_Float16)hid[((size_t)(b * 32 + c)) * NQ + i];
    v[32] = (_Float16)pha[(size_t)b * NQ + i];
#pragma unroll
    for (int c = 33; c < 40; c++) v[c] = (_Float16)0.f;
    _Float16* dst = xt + (size_t)t * 40;
#pragma unroll
    for (int q = 0; q < 5; q++) *(f16x8*)(dst + q * 8) = *(const f16x8*)(v + q * 8);
}

// ================= top-k machinery =================
__global__ void hist_kernel(const float* __restrict__ err, uint32_t* st, int round) {
    __shared__ uint32_t h[256];
    h[threadIdx.x] = 0u;
    __syncthreads();
    int t = blockIdx.x * 256 + threadIdx.x;
    int b = t >> 18;
    uint32_t bits = __float_as_uint(err[t]);
    uint32_t pref = st[b];
    int shift = 24 - 8 * round;
    bool match = (round == 0) || ((bits >> (shift + 8)) == (pref >> (shift + 8)));
    if (match) atomicAdd(&h[(bits >> shift) & 255u], 1u);
    __syncthreads();
    uint32_t v = h[threadIdx.x];
    if (v) atomicAdd(&st[WS_HIST + round * 512 + b * 256 + threadIdx.x], v);
}

__global__ void scan_kernel(uint32_t* st, int round) {
    int b = blockIdx.x;
    int lane = threadIdx.x;
    int shift = 24 - 8 * round;
    const uint32_t* hist = st + WS_HIST + round * 512 + b * 256;
    int binbase = 255 - 4 * lane;
    uint32_t hv0 = hist[binbase], hv1 = hist[binbase - 1],
             hv2 = hist[binbase - 2], hv3 = hist[binbase - 3];
    uint32_t p = hv0 + hv1 + hv2 + hv3;
    uint32_t cum = p;
    for (int o = 1; o < 64; o <<= 1) {
        uint32_t n = __shfl_up(cum, o);
        if (lane >= o) cum += n;
    }
    uint32_t rem = st[2 + b];
    unsigned long long bal = __ballot(cum >= rem);
    int first = __ffsll(bal) - 1;
    if (lane == first) {
        uint32_t acc = cum - p;
        uint32_t hv[4] = {hv0, hv1, hv2, hv3};
        int chosen = binbase;
        for (int q = 0; q < 4; q++) {
            if (acc + hv[q] >= rem) { chosen = binbase - q; break; }
            acc += hv[q];
        }
        uint32_t pref = st[b] | ((uint32_t)chosen << shift);
        st[b] = pref;
        st[2 + b] = rem - acc;
        if (round == 3) { st[4 + b] = pref; st[6 + b] = rem - acc; }
    }
}

// ---- deterministic sorted compact: count -> scan -> place ----
__global__ void ccount_kernel(const float* __restrict__ err, uint32_t* st) {
    __shared__ uint32_t wsum[8];
    int blk = blockIdx.x, tid = threadIdx.x;
    int b = blk >> 9, base = (blk & 511) << 9;
    uint32_t T = st[4 + b];
    uint32_t b0 = __float_as_uint(err[b * NQ + base + tid]);
    uint32_t b1 = __float_as_uint(err[b * NQ + base + 256 + tid]);
    unsigned long long m0 = __ballot(b0 > T);
    unsigned long long m1 = __ballot(b1 > T);
    int w = tid >> 6, lane = tid & 63;
    if (lane == 0) { wsum[w] = (uint32_t)__popcll(m0); wsum[4 + w] = (uint32_t)__popcll(m1); }
    __syncthreads();
    if (tid == 0)
        st[WS_BCNT + blk] = wsum[0] + wsum[1] + wsum[2] + wsum[3]
                          + wsum[4] + wsum[5] + wsum[6] + wsum[7];
}

__global__ void cscan_kernel(uint32_t* st) {      // 2 blocks x 512
    __shared__ uint32_t wtot[8];
    int b = blockIdx.x, tid = threadIdx.x;
    int lane = tid & 63, w = tid >> 6;
    uint32_t v = st[WS_BCNT + b * 512 + tid];
    uint32_t inc = v;
    for (int o = 1; o < 64; o <<= 1) {
        uint32_t n = __shfl_up(inc, o);
        if (lane >= o) inc += n;
    }
    if (lane == 63) wtot[w] = inc;
    __syncthreads();
    uint32_t off = 0;
    for (int j = 0; j < w; j++) off += wtot[j];
    uint32_t base = off + inc - v;
    st[WS_BBASE + b * 512 + tid] = base;
    if (tid == 511) st[8 + b] = base + v;         // selTotal (ties appended after)
}

__global__ void cplace_kernel(const float* __restrict__ err, uint32_t* st,
                              float* __restrict__ refout) {
    __shared__ uint32_t wc[8];
    int blk = blockIdx.x, tid = threadIdx.x;
    int b = blk >> 9, base = (blk & 511) << 9;
    uint32_t T = st[4 + b];
    uint32_t blkbase = st[WS_BBASE + b * 512 + (blk & 511)];
    int i0 = base + tid, i1 = base + 256 + tid;
    uint32_t b0 = __float_as_uint(err[b * NQ + i0]);
    uint32_t b1 = __float_as_uint(err[b * NQ + i1]);
    bool s0 = b0 > T, s1 = b1 > T;
    unsigned long long m0 = __ballot(s0);
    unsigned long long m1 = __ballot(s1);
    int w = tid >> 6, lane = tid & 63;
    if (lane == 0) { wc[w] = (uint32_t)__popcll(m0); wc[4 + w] = (uint32_t)__popcll(m1); }
    refout[b * NQ + i0] = s0 ? 1.0f : 0.0f;
    refout[b * NQ + i1] = s1 ? 1.0f : 0.0f;
    __syncthreads();
    uint32_t tot0 = wc[0] + wc[1] + wc[2] + wc[3];
    uint32_t pre0 = 0, pre1 = tot0;
    for (int j = 0; j < w; j++) { pre0 += wc[j]; pre1 += wc[4 + j]; }
    unsigned long long lt = (1ull << lane) - 1ull;
    if (s0) {
        uint32_t slot = blkbase + pre0 + (uint32_t)__popcll(m0 & lt);
        if (slot < K_SEL) st[WS_SEL + b * K_SEL + slot] = (uint32_t)i0;
    }
    if (s1) {
        uint32_t slot = blkbase + pre1 + (uint32_t)__popcll(m1 & lt);
        if (slot < K_SEL) st[WS_SEL + b * K_SEL + slot] = (uint32_t)i1;
    }
    if (b0 == T) { uint32_t e = atomicAdd(&st[10 + b], 1u); if (e < EQ_CAP) st[WS_EQ + b * EQ_CAP + e] = (uint32_t)i0; }
    if (b1 == T) { uint32_t e = atomicAdd(&st[10 + b], 1u); if (e < EQ_CAP) st[WS_EQ + b * EQ_CAP + e] = (uint32_t)i1; }
}

__global__ void select_kernel(uint32_t* st, float* __restrict__ refout) {
    __shared__ uint32_t L[EQ_CAP];
    int b = blockIdx.x;
    uint32_t m = st[10 + b]; if (m > EQ_CAP) m = EQ_CAP;
    uint32_t need = st[6 + b];
    uint32_t T = st[4 + b];
    for (uint32_t j = threadIdx.x; j < m; j += blockDim.x) L[j] = st[WS_EQ + b * EQ_CAP + j];
    __syncthreads();
    for (uint32_t j = threadIdx.x; j < m; j += blockDim.x) {
        uint32_t idx = L[j];
        uint32_t rank = 0;
        for (uint32_t q = 0; q < m; q++) rank += (L[q] < idx) ? 1u : 0u;
        if (rank < need) {
            uint32_t slot = atomicAdd(&st[8 + b], 1u);
            if (slot < K_SEL) st[WS_SEL + b * K_SEL + slot] = idx;
            refout[b * NQ + idx] = (T != 0u) ? 1.0f : 0.0f;
        }
    }
}

// ================= 4x bilinear upsample of pha =================
__global__ void upsample_kernel(const float* __restrict__ pha, float* __restrict__ out) {
    int t = blockIdx.x * 256 + threadIdx.x;
    int xq = t & 511;
    int rest = t >> 9;
    int oy = rest & 2047;
    int b  = rest >> 11;
    const float* src = pha + (size_t)b * NQ;
    float sy = oy * 0.25f - 0.375f;
    sy = fminf(fmaxf(sy, 0.0f), 511.0f);
    int y0 = (int)sy; int y1i = min(y0 + 1, 511);
    float fy = sy - (float)y0;
    float rv[4];
#pragma unroll
    for (int j = 0; j < 4; j++) {
        int ox = xq * 4 + j;
        float sx = ox * 0.25f - 0.375f;
        sx = fminf(fmaxf(sx, 0.0f), 511.0f);
        int x0 = (int)sx; int x1i = min(x0 + 1, 511);
        float fx = sx - (float)x0;
        float v00 = src[y0 * 512 + x0],  v01 = src[y0 * 512 + x1i];
        float v10 = src[y1i * 512 + x0], v11 = src[y1i * 512 + x1i];
        rv[j] = v00 * (1.f - fy) * (1.f - fx) + v01 * (1.f - fy) * fx
              + v10 * fy * (1.f - fx)         + v11 * fy * fx;
    }
    float4 r4 = make_float4(rv[0], rv[1], rv[2], rv[3]);
    *reinterpret_cast<float4*>(out + (size_t)b * 4194304 + (size_t)oy * 2048 + xq * 4) = r4;
}

// ================= MFMA patch CNN: 2 waves / patch =================
// vs R11 (proven): ONLY the hid-gather block changes when XT=true
// (channels-last f16 vector loads). XT=false path is byte-identical to R11.
__device__ __forceinline__ f16x8 ldfrag(const _Float16* wf, int frag, int l) {
    return *(const f16x8*)(wf + frag * 512 + l * 8);
}

template<bool XT>
__global__ __launch_bounds__(128) void patch_kernel(
    const float* __restrict__ hid, const float* __restrict__ pha,
    const _Float16* __restrict__ xt,
    const char* __restrict__ ws, float* __restrict__ out) {
    __shared__ _Float16 xs[64][40];      // [8x8 pos][ci], ci 0..31 valid
    __shared__ _Float16 y1n[36][40];     // [6x6 pos][oc], oc 0..23 valid, 24..39 zero
    __shared__ _Float16 pool[64][40];    // phaP [48][40] (conv1) then y2u [64][40] (conv3)
    __shared__ float pha8[64];
    __shared__ float biasL[56];
    float* y3s = (float*)&y1n[0][0];     // [36][16] f32 = 2304B <= 2880B (dead after conv2)

    const _Float16* wf = (const _Float16*)ws;
    const float* biasG = (const float*)(ws + BIAS_OFF);
    const float* w4r   = (const float*)(ws + W4_OFF);
    const uint32_t* st = (const uint32_t*)(ws + ST_OFF);

    int tid = threadIdx.x, l = tid & 63, wid = tid >> 6;
    int lo = l & 15, hi = l >> 4;
    int bp = blockIdx.x;
    int b = (bp >= K_SEL) ? 1 : 0;
    int pi = bp - b * K_SEL;
    uint32_t idx = st[WS_SEL + b * K_SEL + pi] & 0x3FFFFu;   // clamp: fault-proof
    int hq = (int)(idx >> 9), wq = (int)(idx & 511u);

    if (tid < 53) biasL[tid] = biasG[tid];

    // ---- gather: lane = 8x8 position, wave = 16-channel half ----
    int ry = l >> 3, rx = l & 7;
    int hy = hq * 2 + ry - 3, hx = wq * 2 + rx - 3;
    bool inb = ((unsigned)hy < 1024u) && ((unsigned)hx < 1024u);
    float sy = fminf(fmaxf(hy * 0.5f - 0.25f, 0.f), 511.f);
    float sx = fminf(fmaxf(hx * 0.5f - 0.25f, 0.f), 511.f);
    int y0 = (int)sy, x0 = (int)sx;
    int y1c = min(y0 + 1, 511), x1c = min(x0 + 1, 511);
    float fy = sy - (float)y0, fx = sx - (float)x0;
    int o00 = y0 * 512 + x0, o01 = y0 * 512 + x1c, o10 = y1c * 512 + x0, o11 = y1c * 512 + x1c;
    float w00 = (1.f - fy) * (1.f - fx), w01 = (1.f - fy) * fx;
    float w10 = fy * (1.f - fx), w11 = fy * fx;

    _Float16 hv[16];
    if (XT) {
        if (inb) {
            const _Float16* xtb = xt + (size_t)b * NQ * 40 + (size_t)wid * 16;
            const _Float16* p00 = xtb + (size_t)o00 * 40;
            const _Float16* p01 = xtb + (size_t)o01 * 40;
            const _Float16* p10 = xtb + (size_t)o10 * 40;
            const _Float16* p11 = xtb + (size_t)o11 * 40;
            f16x8 a0 = *(const f16x8*)p00, a1 = *(const f16x8*)(p00 + 8);
            f16x8 b0 = *(const f16x8*)p01, b1 = *(const f16x8*)(p01 + 8);
            f16x8 c0 = *(const f16x8*)p10, c1 = *(const f16x8*)(p10 + 8);
            f16x8 d0 = *(const f16x8*)p11, d1 = *(const f16x8*)(p11 + 8);
#pragma unroll
            for (int j = 0; j < 8; j++) {
                hv[j]     = (_Float16)(w00 * (float)a0[j] + w01 * (float)b0[j]
                                     + w10 * (float)c0[j] + w11 * (float)d0[j]);
                hv[j + 8] = (_Float16)(w00 * (float)a1[j] + w01 * (float)b1[j]
                                     + w10 * (float)c1[j] + w11 * (float)d1[j]);
            }
        } else {
#pragma unroll
            for (int c = 0; c < 16; c++) hv[c] = (_Float16)0.f;
        }
    } else {
        const float* hb = hid + ((size_t)b * 32 + wid * 16) * NQ;
#pragma unroll
        for (int c = 0; c < 16; c++) {
            const float* p = hb + (size_t)c * NQ;
            float v = 0.f;
            if (inb) v = p[o00] * w00 + p[o01] * w01 + p[o10] * w10 + p[o11] * w11;
            hv[c] = (_Float16)v;
        }
    }
    f16x8 h0 = {hv[0], hv[1], hv[2], hv[3], hv[4], hv[5], hv[6], hv[7]};
    f16x8 h1 = {hv[8], hv[9], hv[10], hv[11], hv[12], hv[13], hv[14], hv[15]};
    {
        _Float16* xrow = &xs[l][wid * 16];
        *(f16x8*)xrow = h0;
        *((f16x8*)xrow + 1) = h1;
    }
    f16x8 z8 = {(_Float16)0.f, (_Float16)0.f, (_Float16)0.f, (_Float16)0.f,
                (_Float16)0.f, (_Float16)0.f, (_Float16)0.f, (_Float16)0.f};
    if (wid == 1) {
        const float* p = pha + (size_t)b * NQ;
        float v = 0.f;
        if (inb) v = p[o00] * w00 + p[o01] * w01 + p[o10] * w10 + p[o11] * w11;
        pha8[l] = v;
    }
    __syncthreads();

    // ---- phaP build (wave0, rows 0..47) + y1n pad-col zero (wave1) ----
    if (wid == 0) {
        if (l < 48) {
            int py = (l * 43) >> 8, px = l - py * 6;
            _Float16 tap[9];
#pragma unroll
            for (int t = 0; t < 9; t++) {
                int ky = t / 3, kx = t % 3;
                int ip = (py + ky) * 8 + px + kx;
                tap[t] = (_Float16)pha8[ip & 63];
            }
            _Float16* row = &pool[l][0];
            f16x8 r0 = {tap[0], tap[1], tap[2], tap[3], tap[4], tap[5], tap[6], tap[7]};
            f16x8 r1 = z8; r1[0] = tap[8];
            *(f16x8*)row = r0;
            *(f16x8*)(row + 8)  = r1;
            *(f16x8*)(row + 16) = z8;
            *(f16x8*)(row + 24) = z8;      // cols 9..31 zero (32..39 never read)
        }
    } else {
        for (int i = l; i < 72; i += 64) {
            *(f16x8*)&y1n[i >> 1][24 + (i & 1) * 8] = z8;   // cols 24..39 of all 36 rows
        }
    }
    __syncthreads();

    // ---- conv1: 33ch -> 24, 8x8 -> 6x6, MFMA ----
    f32x4 zf = {0.f, 0.f, 0.f, 0.f};
    f32x4 aA0 = zf, aA1 = zf, aB = zf;
    int nA = wid * 16 + lo, nB = 32 + lo;
    int pyA = (nA * 43) >> 8, pxA = nA - pyA * 6;
    int pyB = (nB * 43) >> 8, pxB = nB - pyB * 6;
    {   // pha K-tile (taps in k)
        f16x8 A0 = ldfrag(wf, 36, l), A1 = ldfrag(wf, 37, l);
        f16x8 BA = *(const f16x8*)&pool[nA][hi * 8];
        f16x8 BB = *(const f16x8*)&pool[nB][hi * 8];
        aA0 = MFMA16(A0, BA, aA0);
        aA1 = MFMA16(A1, BA, aA1);
        aB  = MFMA16(wid ? A1 : A0, BB, aB);
    }
#pragma unroll
    for (int ky = 0; ky < 3; ky++) {
#pragma unroll
        for (int kt = 0; kt < 3; kt++) {
            f16x8 A0 = ldfrag(wf, ky * 6 + kt * 2 + 0, l);
            f16x8 A1 = ldfrag(wf, ky * 6 + kt * 2 + 1, l);
            int rA = ((pyA + ky) * 8 + pxA + kt) & 63;   // identity for valid n (<36); wraps garbage
            int rB = ((pyB + ky) * 8 + pxB + kt) & 63;
            f16x8 BA = *(const f16x8*)&xs[rA][hi * 8];
            f16x8 BB = *(const f16x8*)&xs[rB][hi * 8];
            aA0 = MFMA16(A0, BA, aA0);
            aA1 = MFMA16(A1, BA, aA1);
            aB  = MFMA16(wid ? A1 : A0, BB, aB);
        }
    }
    // epilogue -> y1n (bias+relu+f16, single write)
    {
        f32x4 accs[3] = {aA0, aA1, aB};
        int mts[3] = {0, 1, wid};
        int nts[3] = {wid, wid, 2};
#pragma unroll
        for (int f = 0; f < 3; f++) {
            int n = nts[f] * 16 + lo;
            int ocb = mts[f] * 16 + hi * 4;
            if (n < 36 && ocb < 24) {
                f16x4 hh;
                hh[0] = (_Float16)fmaxf(accs[f][0] + biasL[ocb + 0], 0.f);
                hh[1] = (_Float16)fmaxf(accs[f][1] + biasL[ocb + 1], 0.f);
                hh[2] = (_Float16)fmaxf(accs[f][2] + biasL[ocb + 2], 0.f);
                hh[3] = (_Float16)fmaxf(accs[f][3] + biasL[ocb + 3], 0.f);
                *(f16x4*)&y1n[n][ocb] = hh;
            }
        }
    }
    __syncthreads();

    // ---- conv2 (wave0): 24ch 6x6 -> 16ch 4x4 ; wave1 zeroes y2u pads ----
    if (wid == 0) {
        f32x4 a2 = zf;
        int qy = lo >> 2, qx = lo & 3;
#pragma unroll
        for (int ky = 0; ky < 3; ky++) {
#pragma unroll
            for (int kt = 0; kt < 3; kt++) {
                f16x8 A = ldfrag(wf, 18 + ky * 3 + kt, l);
                int k = kt * 32 + hi * 8;
                const _Float16* bptr;
                if (k < 72) {
                    int kx = k / 24, ci0 = k - kx * 24;
                    bptr = &y1n[(qy + ky) * 6 + qx + kx][ci0];
                } else {
                    bptr = &y1n[0][24];                   // zeroed pad
                }
                f16x8 B = *(const f16x8*)bptr;
                a2 = MFMA16(A, B, a2);
            }
        }
        int ocb = hi * 4;
        f16x4 hh;
        hh[0] = (_Float16)fmaxf(a2[0] + biasL[24 + ocb + 0], 0.f);
        hh[1] = (_Float16)fmaxf(a2[1] + biasL[24 + ocb + 1], 0.f);
        hh[2] = (_Float16)fmaxf(a2[2] + biasL[24 + ocb + 2], 0.f);
        hh[3] = (_Float16)fmaxf(a2[3] + biasL[24 + ocb + 3], 0.f);
#pragma unroll
        for (int dy = 0; dy < 2; dy++)
#pragma unroll
            for (int dx = 0; dx < 2; dx++) {
                int row = (2 * qy + dy) * 8 + 2 * qx + dx;
                *(f16x4*)&pool[row][ocb] = hh;            // y2u (nearest 2x)
            }
    } else {
        *(f16x8*)&pool[l][16] = z8;                       // y2u pad cols 16..31
        *(f16x8*)&pool[l][24] = z8;
    }
    __syncthreads();

    // ---- conv3: 16ch 8x8 -> 12ch 6x6 ; wave0: nt0, wave1: nt1,nt2 ----
    f32x4 aC = zf, aD = zf;
    int nC = wid * 16 + lo, nD = 32 + lo;
    int pyC = (nC * 43) >> 8, pxC = nC - pyC * 6;
    int pyD = (nD * 43) >> 8, pxD = nD - pyD * 6;
#pragma unroll
    for (int s = 0; s < 9; s++) {
        int ky = s / 3, kx = s % 3;
        f16x8 A = ldfrag(wf, 27 + s, l);
        f16x8 BC = *(const f16x8*)&pool[((pyC + ky) * 8 + pxC + kx) & 63][hi * 8];
        aC = MFMA16(A, BC, aC);
        if (wid) {
            f16x8 BD = *(const f16x8*)&pool[((pyD + ky) * 8 + pxD + kx) & 63][hi * 8];
            aD = MFMA16(A, BD, aD);
        }
    }
    __syncthreads();   // y1n reads done (conv2), safe to overwrite as y3s
    {
        int ocb = hi * 4;
        f32x4 accs[2] = {aC, aD};
        int nts[2] = {wid, 2};
        int cnt = wid ? 2 : 1;
        for (int f = 0; f < cnt; f++) {
            int n = nts[f] * 16 + lo;
            if (n < 36) {
                f32x4 v;
#pragma unroll
                for (int r = 0; r < 4; r++) {
                    float bb = (ocb + r < 12) ? biasL[40 + ocb + r] : 0.f;
                    float x = accs[f][r] + bb;
                    v[r] = (ocb + r < 12) ? fmaxf(x, 0.f) : 0.f;
                }
                *(f32x4*)&y3s[n * 16 + ocb] = v;
            }
        }
    }
    __syncthreads();

    // ---- conv4 (wave0): 12ch 6x6 -> 1ch 4x4, f32, + scatter store ----
    if (wid == 0) {
        int r4 = lo >> 2, c4 = lo & 3, cig = hi;
        float acc = 0.f;
#pragma unroll
        for (int t = 0; t < 9; t++) {
            int ky = t / 3, kx = t % 3;
            const f32x4 xv = *(const f32x4*)&y3s[((r4 + ky) * 6 + c4 + kx) * 16 + cig * 4];
            const f32x4 wv = *(const f32x4*)(w4r + t * 16 + cig * 4);
            acc += xv[0] * wv[0] + xv[1] * wv[1] + xv[2] * wv[2] + xv[3] * wv[3];
        }
        acc += __shfl_xor(acc, 32);
        acc += __shfl_xor(acc, 16);
        if (l < 16) {
            out[(size_t)b * 4194304 + (size_t)(hq * 4 + r4) * 2048 + (wq * 4 + c4)] = acc + biasL[52];
        }
    }
}

extern "C" void kernel_launch(void* const* d_in, const int* in_sizes, int n_in,
                              void* d_out, int out_size, void* d_ws, size_t ws_size,
                              hipStream_t stream) {
    const float* pha = (const float*)d_in[0];
    const float* err = (const float*)d_in[1];
    const float* hid = (const float*)d_in[2];
    const float* w1  = (const float*)d_in[3];
    const float* g1  = (const float*)d_in[4];
    const float* bb1 = (const float*)d_in[5];
    const float* m1  = (const float*)d_in[6];
    const float* v1  = (const float*)d_in[7];
    const float* w2  = (const float*)d_in[8];
    const float* g2  = (const float*)d_in[9];
    const float* bb2 = (const float*)d_in[10];
    const float* m2  = (const float*)d_in[11];
    const float* v2  = (const float*)d_in[12];
    const float* w3  = (const float*)d_in[13];
    const float* g3  = (const float*)d_in[14];
    const float* bb3 = (const float*)d_in[15];
    const float* m3  = (const float*)d_in[16];
    const float* v3  = (const float*)d_in[17];
    const float* w4  = (const float*)d_in[18];
    const float* b4  = (const float*)d_in[19];

    float* out    = (float*)d_out;
    float* refout = out + (size_t)NB * 4194304;
    char* ws      = (char*)d_ws;
    uint32_t* st  = (uint32_t*)(ws + ST_OFF);
    _Float16* xt  = (_Float16*)(ws + XT_OFF);
    bool use_xt   = (ws_size >= WS_NEED);     // constant across calls -> deterministic

    prep_kernel<<<1, 256, 0, stream>>>(w1, g1, bb1, m1, v1, w2, g2, bb2, m2, v2,
                                       w3, g3, bb3, m3, v3, w4, b4, ws);
    if (use_xt)
        transpose_kernel<<<2048, 256, 0, stream>>>(hid, pha, xt);
    for (int r = 0; r < 4; r++) {
        hist_kernel<<<2048, 256, 0, stream>>>(err, st, r);
        scan_kernel<<<2, 64, 0, stream>>>(st, r);
    }
    ccount_kernel<<<1024, 256, 0, stream>>>(err, st);
    cscan_kernel<<<2, 512, 0, stream>>>(st);
    cplace_kernel<<<1024, 256, 0, stream>>>(err, st, refout);
    select_kernel<<<2, 256, 0, stream>>>(st, refout);
    upsample_kernel<<<8192, 256, 0, stream>>>(pha, out);
    if (use_xt)
        patch_kernel<true><<<2 * K_SEL, 128, 0, stream>>>(hid, pha, xt, ws, out);
    else
        patch_kernel<false><<<2 * K_SEL, 128, 0, stream>>>(hid, pha, xt, ws, out);
}